// Round 9
// baseline (426.361 us; speedup 1.0000x reference)
//
#include <hip/hip_runtime.h>
#include <hip/hip_bf16.h>
#include <math.h>

// Problem constants
#define Bn 4
#define Ln 1024
#define Vn 64
#define Dn 256
#define Hn 4
#define DKn 64
#define NLn 4
#define Mn 20
#define FFn 1024
#define NTOK (Bn * Ln)   // 4096
#define QKVW 768         // fused q|k|v width
#define LOG2E 1.4426950408889634f
#define PELEMS (Bn * Hn * Ln * Ln)   // 16777216 elements per layer P

typedef __attribute__((ext_vector_type(8))) short bf16x8;
typedef __attribute__((ext_vector_type(4))) float f32x4;

__device__ __forceinline__ ushort f2b(float f) {   // fp32 -> bf16 RNE
    uint u = __float_as_uint(f);
    u += 0x7fff + ((u >> 16) & 1);
    return (ushort)(u >> 16);
}
__device__ __forceinline__ float b2f(ushort u) {   // exact
    return __uint_as_float(((uint)u) << 16);
}

// ---------------------------------------------------------------------------
__global__ __launch_bounds__(256) void embed_k(const float* __restrict__ X,
                                               const float* __restrict__ E,
                                               ushort* __restrict__ Hb) {
    __shared__ float xs[Vn];
    int n = blockIdx.x, d = threadIdx.x;
    if (threadIdx.x < Vn) xs[threadIdx.x] = X[n * Vn + threadIdx.x];
    __syncthreads();
    float s = 0.f;
#pragma unroll
    for (int v = 0; v < Vn; ++v) s += xs[v] * E[v * Dn + d];
    Hb[(size_t)n * Dn + d] = f2b(s);
}

// ---------------------------------------------------------------------------
// bias tables, pre-scaled into exp2 domain
__global__ __launch_bounds__(256) void relbias_k(const float* __restrict__ rk,
                                                 const float* __restrict__ rb,
                                                 float* __restrict__ bkT,
                                                 float* __restrict__ bbT) {
    int tid = blockIdx.x * 256 + threadIdx.x;   // < NL*H*1024
    int dist = tid & 1023;
    int hh = (tid >> 10) & 3;
    int l = tid >> 12;
    float dd = (float)dist;
    if (dist > Mn) dd = (float)Mn + log2f((float)(dist - Mn));
    if (dd > 2.0f * Mn) dd = 2.0f * Mn;
    int idx = (int)dd;
    bkT[tid] = rk[(l * (2 * Mn + 1) + idx) * Hn + hh] * 0.125f * LOG2E;
    bbT[tid] = rb[(l * (2 * Mn + 1) + idx) * Hn + hh] * LOG2E;
}

// ---------------------------------------------------------------------------
__global__ __launch_bounds__(256) void prep_bias(const float* __restrict__ bq,
                                                 const float* __restrict__ bk,
                                                 const float* __restrict__ bv,
                                                 float* __restrict__ bqkv) {
    int idx = blockIdx.x * 256 + threadIdx.x;   // < NL*768
    int l = idx / QKVW, r = idx - l * QKVW;
    float v;
    if (r < 256)      v = bq[l * 256 + r];
    else if (r < 512) v = bk[l * 256 + r - 256];
    else              v = bv[l * 256 + r - 512];
    bqkv[idx] = v;
}

// ---------------------------------------------------------------------------
// Weight transpose + fp32->bf16: dst[c][r] = src[r][c]; grid.z = layer.
__global__ __launch_bounds__(256) void transpose_cvt(
    const float* __restrict__ src, ushort* __restrict__ dst,
    int R, int C, int srcLS, int dstLS) {
    __shared__ float s[32][33];
    src += (size_t)blockIdx.z * srcLS;
    dst += (size_t)blockIdx.z * dstLS;
    int r0 = blockIdx.y * 32, c0 = blockIdx.x * 32;
    int tx = threadIdx.x & 31, ty = threadIdx.x >> 5;
#pragma unroll
    for (int ii = 0; ii < 4; ++ii)
        s[ty + 8 * ii][tx] = src[(size_t)(r0 + ty + 8 * ii) * C + c0 + tx];
    __syncthreads();
#pragma unroll
    for (int ii = 0; ii < 4; ++ii)
        dst[(size_t)(c0 + ty + 8 * ii) * R + r0 + tx] = f2b(s[tx][ty + 8 * ii]);
}

// ---------------------------------------------------------------------------
// V transpose per (b,h): Vt[bh][d][j] = qkvb[b*L+j][512 + h*64 + d]
__global__ __launch_bounds__(256) void transpose_v(const ushort* __restrict__ qkv,
                                                   ushort* __restrict__ Vt) {
    __shared__ ushort s[32][65];
    int j0 = blockIdx.x * 32;
    int bh = blockIdx.y;
    int b = bh >> 2, hh = bh & 3;
    int t = threadIdx.x;
#pragma unroll
    for (int ii = 0; ii < 8; ++ii) {
        int e = t + 256 * ii;          // 2048 = 32 j x 64 d
        int jr = e >> 6, dc = e & 63;
        s[jr][dc] = qkv[(size_t)(b * Ln + j0 + jr) * QKVW + 2 * Dn + hh * DKn + dc];
    }
    __syncthreads();
#pragma unroll
    for (int ii = 0; ii < 8; ++ii) {
        int e = t + 256 * ii;          // 2048 = 64 d x 32 j
        int dr = e >> 5, jc = e & 31;
        Vt[(size_t)(bh * DKn + dr) * Ln + j0 + jc] = s[jc][dr];
    }
}

// ---------------------------------------------------------------------------
// bf16 MFMA GEMM: C[m][n] = act(sum_k A[m][k]*Bt[n][k] + bias[n]), C bf16.
#define GST 40
__global__ __launch_bounds__(256) void gemm_mfma(
    const ushort* __restrict__ A, const ushort* __restrict__ Bt,
    const float* __restrict__ bias, ushort* __restrict__ C,
    int M, int N, int K, int act) {
    __shared__ __align__(16) ushort As[64 * GST];
    __shared__ __align__(16) ushort Bs[64 * GST];
    int t = threadIdx.x;
    int lane = t & 63, w = t >> 6;
    int wm = w >> 1, wn = w & 1;
    int l15 = lane & 15, lg = lane >> 4;
    int mBase = blockIdx.y * 64, nBase = blockIdx.x * 64;
    int lrow = t >> 2, lkc = (t & 3) * 8;
    const ushort* Ap = A + (size_t)(mBase + lrow) * K + lkc;
    const ushort* Bp = Bt + (size_t)(nBase + lrow) * K + lkc;
    f32x4 acc[2][2] = {};
    for (int k0 = 0; k0 < K; k0 += 32) {
        uint4 av = *(const uint4*)(Ap + k0);
        uint4 bv = *(const uint4*)(Bp + k0);
        __syncthreads();
        *(uint4*)&As[lrow * GST + lkc] = av;
        *(uint4*)&Bs[lrow * GST + lkc] = bv;
        __syncthreads();
        bf16x8 a0 = *(const bf16x8*)&As[(wm * 32 + l15) * GST + lg * 8];
        bf16x8 a1 = *(const bf16x8*)&As[(wm * 32 + 16 + l15) * GST + lg * 8];
        bf16x8 b0 = *(const bf16x8*)&Bs[(wn * 32 + l15) * GST + lg * 8];
        bf16x8 b1 = *(const bf16x8*)&Bs[(wn * 32 + 16 + l15) * GST + lg * 8];
        acc[0][0] = __builtin_amdgcn_mfma_f32_16x16x32_bf16(a0, b0, acc[0][0], 0, 0, 0);
        acc[0][1] = __builtin_amdgcn_mfma_f32_16x16x32_bf16(a0, b1, acc[0][1], 0, 0, 0);
        acc[1][0] = __builtin_amdgcn_mfma_f32_16x16x32_bf16(a1, b0, acc[1][0], 0, 0, 0);
        acc[1][1] = __builtin_amdgcn_mfma_f32_16x16x32_bf16(a1, b1, acc[1][1], 0, 0, 0);
    }
#pragma unroll
    for (int ni = 0; ni < 2; ++ni) {
        int col = nBase + wn * 32 + ni * 16 + l15;
        float bc = bias[col];
#pragma unroll
        for (int mi = 0; mi < 2; ++mi) {
            int rb = mBase + wm * 32 + mi * 16 + lg * 4;
#pragma unroll
            for (int j = 0; j < 4; ++j) {
                float v = acc[mi][ni][j] + bc;
                if (act) v = v * 0.5f * (1.0f + erff(v * 0.7071067811865475f));
                C[(size_t)(rb + j) * N + col] = f2b(v);
            }
        }
    }
}

// ---------------------------------------------------------------------------
// MFMA flash attention. MODE 0: f32 RMW into avg (fallback).
// MODE 1: stream P as bf16 (ushort4 via LDS readback) to Pout; avg summed later.
#define PWST 40   // ushort stride per P row (80B, 16B-aligned)
template <int MODE>
__global__ __launch_bounds__(256) void attn_fused(
    const ushort* __restrict__ qkv, const ushort* __restrict__ Vt,
    const float* __restrict__ bkTab, const float* __restrict__ bbTab,
    ushort* __restrict__ ctx, float* __restrict__ avg,
    ushort* __restrict__ Pout, int first) {
    __shared__ float bk_l[Ln];
    __shared__ float bb_l[Ln];
    __shared__ __align__(16) ushort Pw[4][2][16 * PWST];  // [wave][hi/lo][i][k32]
    __shared__ float mm[4][16];
    __shared__ float ll[4][16];
    __shared__ float Opart[4][1024];                      // [wave][d*16+i]

    int t = threadIdx.x;
    int lane = t & 63, wn = t >> 6;       // wave = k-slice quarter
    int l15 = lane & 15, lg = lane >> 4;

    int bid = blockIdx.x;
    int xcd = bid & 7, sub = bid >> 3;    // sub in [0,128)
    int bh = xcd * 2 + (sub >> 6);
    int q = sub & 63;
    int b = bh >> 2, hh = bh & 3;
    int i0 = q * 16;

#pragma unroll
    for (int ii = 0; ii < 4; ++ii) {
        bk_l[t + 256 * ii] = bkTab[hh * Ln + t + 256 * ii];
        bb_l[t + 256 * ii] = bbTab[hh * Ln + t + 256 * ii];
    }
    __syncthreads();

    // Q fragment (A-operand): row = i0 + l15, k = lg*8 (+32)
    bf16x8 qa0, qa1;
    {
        const ushort* qp = qkv + (size_t)(b * Ln + i0 + l15) * QKVW + hh * DKn;
        qa0 = *(const bf16x8*)(qp + lg * 8);
        qa1 = *(const bf16x8*)(qp + 32 + lg * 8);
    }

    const ushort* kbase = qkv + (size_t)(b * Ln) * QKVW + Dn + hh * DKn;

    // ---- QK pass: S kept in registers (fully unrolled, barrier-free) -------
    f32x4 sv[16];
    float m[4] = {-1e30f, -1e30f, -1e30f, -1e30f};
#pragma unroll
    for (int c = 0; c < 16; ++c) {
        const ushort* kp = kbase + (size_t)(c * 64 + wn * 16 + l15) * QKVW;
        bf16x8 k0 = *(const bf16x8*)(kp + lg * 8);
        bf16x8 k1 = *(const bf16x8*)(kp + 32 + lg * 8);
        f32x4 acc = {};
        acc = __builtin_amdgcn_mfma_f32_16x16x32_bf16(qa0, k0, acc, 0, 0, 0);
        acc = __builtin_amdgcn_mfma_f32_16x16x32_bf16(qa1, k1, acc, 0, 0, 0);
        int j = c * 64 + wn * 16 + l15;
#pragma unroll
        for (int r = 0; r < 4; ++r) {
            int i = i0 + lg * 4 + r;
            int dist = (i > j) ? (i - j) : (j - i);
            float s = acc[r] * bk_l[dist] + bb_l[dist];
            sv[c][r] = s;
            m[r] = fmaxf(m[r], s);
        }
    }
    // merge max over the 16 l15-lanes
#pragma unroll
    for (int mask = 1; mask < 16; mask <<= 1)
#pragma unroll
        for (int r = 0; r < 4; ++r) m[r] = fmaxf(m[r], __shfl_xor(m[r], mask, 64));
    // merge max across the 4 waves
    if (l15 == 0)
#pragma unroll
        for (int r = 0; r < 4; ++r) mm[wn][lg * 4 + r] = m[r];
    __syncthreads();
#pragma unroll
    for (int r = 0; r < 4; ++r) {
        int row = lg * 4 + r;
        m[r] = fmaxf(fmaxf(mm[0][row], mm[1][row]), fmaxf(mm[2][row], mm[3][row]));
    }
    // p_unnorm = exp2(s - m); accumulate row sums
    float lsum[4] = {0.f, 0.f, 0.f, 0.f};
#pragma unroll
    for (int c = 0; c < 16; ++c)
#pragma unroll
        for (int r = 0; r < 4; ++r) {
            float p = exp2f(sv[c][r] - m[r]);
            sv[c][r] = p;
            lsum[r] += p;
        }
#pragma unroll
    for (int mask = 1; mask < 16; mask <<= 1)
#pragma unroll
        for (int r = 0; r < 4; ++r) lsum[r] += __shfl_xor(lsum[r], mask, 64);
    if (l15 == 0)
#pragma unroll
        for (int r = 0; r < 4; ++r) ll[wn][lg * 4 + r] = lsum[r];
    __syncthreads();
    float invl[4];
#pragma unroll
    for (int r = 0; r < 4; ++r) {
        int row = lg * 4 + r;
        invl[r] = 1.0f / (ll[0][row] + ll[1][row] + ll[2][row] + ll[3][row]);
    }

    // ---- PV partial-O + P output: ZERO barriers -----------------------------
    const ushort* vbase = Vt + (size_t)bh * DKn * Ln;       // [64 d][Ln k]
    float* avgrow = avg + ((size_t)bh * Ln + i0) * Ln;      // MODE 0
    ushort* prow = Pout + ((size_t)bh * Ln + i0) * Ln;      // MODE 1
    int iw = lane >> 2, jq = lane & 3;                      // MODE 1 P-store map
    f32x4 acco[4] = {};
#pragma unroll
    for (int p = 0; p < 8; ++p) {
        const int c0 = 2 * p, c1 = 2 * p + 1;
        float aold[2][4];
        if (MODE == 0 && !first) {
#pragma unroll
            for (int cc = 0; cc < 2; ++cc)
#pragma unroll
                for (int r = 0; r < 4; ++r)
                    aold[cc][r] = avgrow[(size_t)(lg * 4 + r) * Ln +
                                         (c0 + cc) * 64 + wn * 16 + l15];
        }
        // stage P (hi/lo) into wave-private LDS
        float pn[2][4];
#pragma unroll
        for (int cc = 0; cc < 2; ++cc)
#pragma unroll
            for (int r = 0; r < 4; ++r) {
                float pv = sv[c0 + cc][r] * invl[r];
                pn[cc][r] = pv;
                ushort ph = f2b(pv);
                int off = (lg * 4 + r) * PWST + cc * 16 + l15;
                Pw[wn][0][off] = ph;
                Pw[wn][1][off] = f2b(pv - b2f(ph));
            }
        // V A-fragments
        int kcol = (lg < 2 ? c0 : c1) * 64 + wn * 16 + (lg & 1) * 8;
        bf16x8 va0 = *(const bf16x8*)(vbase + (size_t)(0 * 16 + l15) * Ln + kcol);
        bf16x8 va1 = *(const bf16x8*)(vbase + (size_t)(1 * 16 + l15) * Ln + kcol);
        bf16x8 va2 = *(const bf16x8*)(vbase + (size_t)(2 * 16 + l15) * Ln + kcol);
        bf16x8 va3 = *(const bf16x8*)(vbase + (size_t)(3 * 16 + l15) * Ln + kcol);
        // B fragments from own LDS (same-wave RAW: compiler lgkmcnt)
        bf16x8 pbh = *(const bf16x8*)&Pw[wn][0][l15 * PWST + lg * 8];
        bf16x8 pbl = *(const bf16x8*)&Pw[wn][1][l15 * PWST + lg * 8];
        acco[0] = __builtin_amdgcn_mfma_f32_16x16x32_bf16(va0, pbh, acco[0], 0, 0, 0);
        acco[1] = __builtin_amdgcn_mfma_f32_16x16x32_bf16(va1, pbh, acco[1], 0, 0, 0);
        acco[2] = __builtin_amdgcn_mfma_f32_16x16x32_bf16(va2, pbh, acco[2], 0, 0, 0);
        acco[3] = __builtin_amdgcn_mfma_f32_16x16x32_bf16(va3, pbh, acco[3], 0, 0, 0);
        acco[0] = __builtin_amdgcn_mfma_f32_16x16x32_bf16(va0, pbl, acco[0], 0, 0, 0);
        acco[1] = __builtin_amdgcn_mfma_f32_16x16x32_bf16(va1, pbl, acco[1], 0, 0, 0);
        acco[2] = __builtin_amdgcn_mfma_f32_16x16x32_bf16(va2, pbl, acco[2], 0, 0, 0);
        acco[3] = __builtin_amdgcn_mfma_f32_16x16x32_bf16(va3, pbl, acco[3], 0, 0, 0);
        if (MODE == 0) {
            // avg RMW stores
#pragma unroll
            for (int cc = 0; cc < 2; ++cc)
#pragma unroll
                for (int r = 0; r < 4; ++r) {
                    float v = 0.25f * pn[cc][r];
                    if (!first) v += aold[cc][r];
                    avgrow[(size_t)(lg * 4 + r) * Ln + (c0 + cc) * 64 + wn * 16 + l15] = v;
                }
        } else {
            // P bf16 streaming store: lane (iw=lane>>2, jq=lane&3) reads 4
            // consecutive hi ushorts from Pw (8B) and stores ushort4.
            ushort4 ph0 = *(const ushort4*)&Pw[wn][0][iw * PWST + 0 * 16 + jq * 4];
            ushort4 ph1 = *(const ushort4*)&Pw[wn][0][iw * PWST + 1 * 16 + jq * 4];
            *(ushort4*)&prow[(size_t)iw * Ln + c0 * 64 + wn * 16 + jq * 4] = ph0;
            *(ushort4*)&prow[(size_t)iw * Ln + c1 * 64 + wn * 16 + jq * 4] = ph1;
        }
    }

    // ---- reduce partial O across the 4 waves (single barrier) ---------------
#pragma unroll
    for (int dg = 0; dg < 4; ++dg)
#pragma unroll
        for (int r = 0; r < 4; ++r)
            Opart[wn][(dg * 16 + lg * 4 + r) * 16 + l15] = acco[dg][r];
    __syncthreads();
#pragma unroll
    for (int k = 0; k < 4; ++k) {
        int idx = t + 256 * k;          // idx = d*16 + i
        float v = Opart[0][idx] + Opart[1][idx] + Opart[2][idx] + Opart[3][idx];
        int dd = idx >> 4, ii = idx & 15;
        ctx[(size_t)(b * Ln + i0 + ii) * Dn + hh * DKn + dd] = f2b(v);
    }
}

// ---------------------------------------------------------------------------
// avg = 0.25 * (P0 + P1 + P2 + P3), pure streaming. 4 elements per thread.
__global__ __launch_bounds__(256) void avg_sum_k(const ushort* __restrict__ P,
                                                 float* __restrict__ avg) {
    size_t e = ((size_t)blockIdx.x * 256 + threadIdx.x) * 4;
    ushort4 a = *(const ushort4*)&P[e];
    ushort4 b4 = *(const ushort4*)&P[(size_t)PELEMS + e];
    ushort4 c4 = *(const ushort4*)&P[(size_t)2 * PELEMS + e];
    ushort4 d4 = *(const ushort4*)&P[(size_t)3 * PELEMS + e];
    float4 o;
    o.x = 0.25f * (b2f(a.x) + b2f(b4.x) + b2f(c4.x) + b2f(d4.x));
    o.y = 0.25f * (b2f(a.y) + b2f(b4.y) + b2f(c4.y) + b2f(d4.y));
    o.z = 0.25f * (b2f(a.z) + b2f(b4.z) + b2f(c4.z) + b2f(d4.z));
    o.w = 0.25f * (b2f(a.w) + b2f(b4.w) + b2f(c4.w) + b2f(d4.w));
    *(float4*)&avg[e] = o;
}

// ---------------------------------------------------------------------------
__global__ __launch_bounds__(256) void layernorm_k(const ushort* __restrict__ X,
                                                   const float* __restrict__ g,
                                                   const float* __restrict__ bta,
                                                   ushort* __restrict__ Y) {
    int w = threadIdx.x >> 6, lane = threadIdx.x & 63;
    int row = blockIdx.x * 4 + w;
    const ushort* xr = X + (size_t)row * Dn;
    float x[4];
#pragma unroll
    for (int ii = 0; ii < 4; ++ii) x[ii] = b2f(xr[lane + 64 * ii]);
    float s = x[0] + x[1] + x[2] + x[3];
#pragma unroll
    for (int m = 1; m < 64; m <<= 1) s += __shfl_xor(s, m, 64);
    float mu = s * (1.0f / 256.0f);
    float vs = 0.f;
#pragma unroll
    for (int ii = 0; ii < 4; ++ii) {
        float d = x[ii] - mu;
        vs += d * d;
    }
#pragma unroll
    for (int m = 1; m < 64; m <<= 1) vs += __shfl_xor(vs, m, 64);
    float rs = rsqrtf(vs * (1.0f / 256.0f) + 1e-5f);
#pragma unroll
    for (int ii = 0; ii < 4; ++ii) {
        int d = lane + 64 * ii;
        Y[(size_t)row * Dn + d] = f2b((x[ii] - mu) * rs * g[d] + bta[d]);
    }
}

// ---------------------------------------------------------------------------
__global__ __launch_bounds__(256) void mean_part_k(const ushort* __restrict__ Hb,
                                                   float* __restrict__ part) {
    int blk = blockIdx.x;            // 64 = 4 b x 16 groups
    int b = blk >> 4, g = blk & 15;
    int d = threadIdx.x;
    float s = 0.f;
#pragma unroll
    for (int r = 0; r < 64; ++r)
        s += b2f(Hb[(size_t)(b * Ln + g * 64 + r) * Dn + d]);
    part[(size_t)blk * Dn + d] = s;
}
__global__ __launch_bounds__(256) void mean_final_k(const float* __restrict__ part,
                                                    float* __restrict__ out) {
    int b = blockIdx.x, d = threadIdx.x;
    float s = 0.f;
#pragma unroll
    for (int g = 0; g < 16; ++g) s += part[(size_t)(b * 16 + g) * Dn + d];
    out[b * Dn + d] = s * (1.0f / (float)Ln);
}

// ---------------------------------------------------------------------------
extern "C" void kernel_launch(void* const* d_in, const int* in_sizes, int n_in,
                              void* d_out, int out_size, void* d_ws, size_t ws_size,
                              hipStream_t stream) {
    const float* x    = (const float*)d_in[0];
    const float* emb  = (const float*)d_in[1];
    const float* Wq   = (const float*)d_in[2];
    const float* bq   = (const float*)d_in[3];
    const float* Wk   = (const float*)d_in[4];
    const float* bk   = (const float*)d_in[5];
    const float* Wv   = (const float*)d_in[6];
    const float* bv   = (const float*)d_in[7];
    const float* Wo   = (const float*)d_in[8];
    const float* bo   = (const float*)d_in[9];
    const float* rk   = (const float*)d_in[10];
    const float* rb   = (const float*)d_in[11];
    const float* ln1g = (const float*)d_in[12];
    const float* ln1b = (const float*)d_in[13];
    const float* W1   = (const float*)d_in[14];
    const float* b1   = (const float*)d_in[15];
    const float* W2   = (const float*)d_in[16];
    const float* b2   = (const float*)d_in[17];
    const float* ln2g = (const float*)d_in[18];
    const float* ln2b = (const float*)d_in[19];

    float* out = (float*)d_out;
    float* avg = out + Bn * Dn;

    char* ws = (char*)d_ws;
    const size_t MB = 1024 * 1024;
    ushort* hb   = (ushort*)(ws);             // 2 MB
    ushort* qkvb = (ushort*)(ws + 2 * MB);    // 6 MB
    ushort* ctxb = (ushort*)(ws + 8 * MB);    // 2 MB
    ushort* t1   = (ushort*)(ws + 10 * MB);   // 2 MB
    ushort* ffb  = (ushort*)(ws + 12 * MB);   // 8 MB
    ushort* qkvT = (ushort*)(ws + 20 * MB);   // 1.5 MB
    ushort* WoT  = (ushort*)(ws + 22 * MB);   // 0.5 MB
    ushort* W1T  = (ushort*)(ws + 23 * MB);   // 2 MB
    ushort* W2T  = (ushort*)(ws + 25 * MB);   // 2 MB
    float*  bqkv = (float*)(ws + 27 * MB);
    float*  bkT  = (float*)(ws + 27 * MB + 65536);
    float*  bbT  = (float*)(ws + 27 * MB + 131072);
    ushort* Vt   = (ushort*)(ws + 30 * MB);   // 2 MB
    float*  mpart= (float*)(ws + 33 * MB);    // 64 KB
    ushort* Pbuf = (ushort*)(ws + 36 * MB);   // 4 x 32 MB (mode 1 only)

    const size_t need = 36 * MB + (size_t)4 * PELEMS * sizeof(ushort);
    const bool fancy = (ws_size >= need);

    embed_k<<<NTOK, 256, 0, stream>>>(x, emb, hb);
    relbias_k<<<64, 256, 0, stream>>>(rk, rb, bkT, bbT);
    prep_bias<<<12, 256, 0, stream>>>(bq, bk, bv, bqkv);

    dim3 t88(8, 8, NLn);
    transpose_cvt<<<t88, 256, 0, stream>>>(Wq, qkvT + 0,      256, 256, 65536, 196608);
    transpose_cvt<<<t88, 256, 0, stream>>>(Wk, qkvT + 65536,  256, 256, 65536, 196608);
    transpose_cvt<<<t88, 256, 0, stream>>>(Wv, qkvT + 131072, 256, 256, 65536, 196608);
    transpose_cvt<<<t88, 256, 0, stream>>>(Wo, WoT,           256, 256, 65536, 65536);
    transpose_cvt<<<dim3(32, 8, NLn), 256, 0, stream>>>(W1, W1T, 256, 1024, 262144, 262144);
    transpose_cvt<<<dim3(8, 32, NLn), 256, 0, stream>>>(W2, W2T, 1024, 256, 262144, 262144);

    for (int l = 0; l < NLn; ++l) {
        gemm_mfma<<<dim3(12, 64), 256, 0, stream>>>(
            hb, qkvT + (size_t)l * 196608, bqkv + l * QKVW, qkvb, NTOK, QKVW, Dn, 0);
        transpose_v<<<dim3(32, 16), 256, 0, stream>>>(qkvb, Vt);
        if (fancy) {
            attn_fused<1><<<1024, 256, 0, stream>>>(
                qkvb, Vt, bkT + l * Hn * Ln, bbT + l * Hn * Ln, ctxb, avg,
                Pbuf + (size_t)l * PELEMS, (l == 0) ? 1 : 0);
        } else {
            attn_fused<0><<<1024, 256, 0, stream>>>(
                qkvb, Vt, bkT + l * Hn * Ln, bbT + l * Hn * Ln, ctxb, avg,
                (ushort*)Pbuf, (l == 0) ? 1 : 0);
        }
        gemm_mfma<<<dim3(4, 64), 256, 0, stream>>>(
            ctxb, WoT + (size_t)l * 65536, bo + l * 256, t1, NTOK, Dn, Dn, 0);
        layernorm_k<<<NTOK / 4, 256, 0, stream>>>(
            t1, ln1g + l * 256, ln1b + l * 256, t1);
        gemm_mfma<<<dim3(16, 64), 256, 0, stream>>>(
            t1, W1T + (size_t)l * 262144, b1 + l * FFn, ffb, NTOK, FFn, Dn, 1);
        gemm_mfma<<<dim3(4, 64), 256, 0, stream>>>(
            ffb, W2T + (size_t)l * 262144, b2 + l * 256, hb, NTOK, Dn, FFn, 0);
        layernorm_k<<<NTOK / 4, 256, 0, stream>>>(
            hb, ln2g + l * 256, ln2b + l * 256, hb);
    }
    if (fancy) {
        avg_sum_k<<<PELEMS / (256 * 4), 256, 0, stream>>>(Pbuf, avg);
    }
    mean_part_k<<<64, 256, 0, stream>>>(hb, mpart);
    mean_final_k<<<Bn, 256, 0, stream>>>(mpart, out);
}

// Round 10
// 419.311 us; speedup vs baseline: 1.0168x; 1.0168x over previous
//
#include <hip/hip_runtime.h>
#include <hip/hip_bf16.h>
#include <math.h>

// Problem constants
#define Bn 4
#define Ln 1024
#define Vn 64
#define Dn 256
#define Hn 4
#define DKn 64
#define NLn 4
#define Mn 20
#define FFn 1024
#define NTOK (Bn * Ln)   // 4096
#define QKVW 768         // fused q|k|v width
#define LOG2E 1.4426950408889634f
#define PELEMS (Bn * Hn * Ln * Ln)   // 16777216 elements per layer P

typedef __attribute__((ext_vector_type(8))) short bf16x8;
typedef __attribute__((ext_vector_type(4))) float f32x4;

__device__ __forceinline__ ushort f2b(float f) {   // fp32 -> bf16 RNE
    uint u = __float_as_uint(f);
    u += 0x7fff + ((u >> 16) & 1);
    return (ushort)(u >> 16);
}
__device__ __forceinline__ float b2f(ushort u) {   // exact
    return __uint_as_float(((uint)u) << 16);
}

// ---------------------------------------------------------------------------
__global__ __launch_bounds__(256) void embed_k(const float* __restrict__ X,
                                               const float* __restrict__ E,
                                               ushort* __restrict__ Hb) {
    __shared__ float xs[Vn];
    int n = blockIdx.x, d = threadIdx.x;
    if (threadIdx.x < Vn) xs[threadIdx.x] = X[n * Vn + threadIdx.x];
    __syncthreads();
    float s = 0.f;
#pragma unroll
    for (int v = 0; v < Vn; ++v) s += xs[v] * E[v * Dn + d];
    Hb[(size_t)n * Dn + d] = f2b(s);
}

// ---------------------------------------------------------------------------
// bias tables, pre-scaled into exp2 domain
__global__ __launch_bounds__(256) void relbias_k(const float* __restrict__ rk,
                                                 const float* __restrict__ rb,
                                                 float* __restrict__ bkT,
                                                 float* __restrict__ bbT) {
    int tid = blockIdx.x * 256 + threadIdx.x;   // < NL*H*1024
    int dist = tid & 1023;
    int hh = (tid >> 10) & 3;
    int l = tid >> 12;
    float dd = (float)dist;
    if (dist > Mn) dd = (float)Mn + log2f((float)(dist - Mn));
    if (dd > 2.0f * Mn) dd = 2.0f * Mn;
    int idx = (int)dd;
    bkT[tid] = rk[(l * (2 * Mn + 1) + idx) * Hn + hh] * 0.125f * LOG2E;
    bbT[tid] = rb[(l * (2 * Mn + 1) + idx) * Hn + hh] * LOG2E;
}

// ---------------------------------------------------------------------------
__global__ __launch_bounds__(256) void prep_bias(const float* __restrict__ bq,
                                                 const float* __restrict__ bk,
                                                 const float* __restrict__ bv,
                                                 float* __restrict__ bqkv) {
    int idx = blockIdx.x * 256 + threadIdx.x;   // < NL*768
    int l = idx / QKVW, r = idx - l * QKVW;
    float v;
    if (r < 256)      v = bq[l * 256 + r];
    else if (r < 512) v = bk[l * 256 + r - 256];
    else              v = bv[l * 256 + r - 512];
    bqkv[idx] = v;
}

// ---------------------------------------------------------------------------
// Weight transpose + fp32->bf16: dst[c][r] = src[r][c]; grid.z = layer.
__global__ __launch_bounds__(256) void transpose_cvt(
    const float* __restrict__ src, ushort* __restrict__ dst,
    int R, int C, int srcLS, int dstLS) {
    __shared__ float s[32][33];
    src += (size_t)blockIdx.z * srcLS;
    dst += (size_t)blockIdx.z * dstLS;
    int r0 = blockIdx.y * 32, c0 = blockIdx.x * 32;
    int tx = threadIdx.x & 31, ty = threadIdx.x >> 5;
#pragma unroll
    for (int ii = 0; ii < 4; ++ii)
        s[ty + 8 * ii][tx] = src[(size_t)(r0 + ty + 8 * ii) * C + c0 + tx];
    __syncthreads();
#pragma unroll
    for (int ii = 0; ii < 4; ++ii)
        dst[(size_t)(c0 + ty + 8 * ii) * R + r0 + tx] = f2b(s[tx][ty + 8 * ii]);
}

// ---------------------------------------------------------------------------
// V transpose per (b,h): Vt[bh][d][j] = qkvb[b*L+j][512 + h*64 + d]
__global__ __launch_bounds__(256) void transpose_v(const ushort* __restrict__ qkv,
                                                   ushort* __restrict__ Vt) {
    __shared__ ushort s[32][65];
    int j0 = blockIdx.x * 32;
    int bh = blockIdx.y;
    int b = bh >> 2, hh = bh & 3;
    int t = threadIdx.x;
#pragma unroll
    for (int ii = 0; ii < 8; ++ii) {
        int e = t + 256 * ii;          // 2048 = 32 j x 64 d
        int jr = e >> 6, dc = e & 63;
        s[jr][dc] = qkv[(size_t)(b * Ln + j0 + jr) * QKVW + 2 * Dn + hh * DKn + dc];
    }
    __syncthreads();
#pragma unroll
    for (int ii = 0; ii < 8; ++ii) {
        int e = t + 256 * ii;          // 2048 = 64 d x 32 j
        int dr = e >> 5, jc = e & 31;
        Vt[(size_t)(bh * DKn + dr) * Ln + j0 + jc] = s[jc][dr];
    }
}

// ---------------------------------------------------------------------------
// bf16 MFMA GEMM: C[m][n] = act(sum_k A[m][k]*Bt[n][k] + bias[n]), C bf16.
#define GST 40
__global__ __launch_bounds__(256) void gemm_mfma(
    const ushort* __restrict__ A, const ushort* __restrict__ Bt,
    const float* __restrict__ bias, ushort* __restrict__ C,
    int M, int N, int K, int act) {
    __shared__ __align__(16) ushort As[64 * GST];
    __shared__ __align__(16) ushort Bs[64 * GST];
    int t = threadIdx.x;
    int lane = t & 63, w = t >> 6;
    int wm = w >> 1, wn = w & 1;
    int l15 = lane & 15, lg = lane >> 4;
    int mBase = blockIdx.y * 64, nBase = blockIdx.x * 64;
    int lrow = t >> 2, lkc = (t & 3) * 8;
    const ushort* Ap = A + (size_t)(mBase + lrow) * K + lkc;
    const ushort* Bp = Bt + (size_t)(nBase + lrow) * K + lkc;
    f32x4 acc[2][2] = {};
    for (int k0 = 0; k0 < K; k0 += 32) {
        uint4 av = *(const uint4*)(Ap + k0);
        uint4 bv = *(const uint4*)(Bp + k0);
        __syncthreads();
        *(uint4*)&As[lrow * GST + lkc] = av;
        *(uint4*)&Bs[lrow * GST + lkc] = bv;
        __syncthreads();
        bf16x8 a0 = *(const bf16x8*)&As[(wm * 32 + l15) * GST + lg * 8];
        bf16x8 a1 = *(const bf16x8*)&As[(wm * 32 + 16 + l15) * GST + lg * 8];
        bf16x8 b0 = *(const bf16x8*)&Bs[(wn * 32 + l15) * GST + lg * 8];
        bf16x8 b1 = *(const bf16x8*)&Bs[(wn * 32 + 16 + l15) * GST + lg * 8];
        acc[0][0] = __builtin_amdgcn_mfma_f32_16x16x32_bf16(a0, b0, acc[0][0], 0, 0, 0);
        acc[0][1] = __builtin_amdgcn_mfma_f32_16x16x32_bf16(a0, b1, acc[0][1], 0, 0, 0);
        acc[1][0] = __builtin_amdgcn_mfma_f32_16x16x32_bf16(a1, b0, acc[1][0], 0, 0, 0);
        acc[1][1] = __builtin_amdgcn_mfma_f32_16x16x32_bf16(a1, b1, acc[1][1], 0, 0, 0);
    }
#pragma unroll
    for (int ni = 0; ni < 2; ++ni) {
        int col = nBase + wn * 32 + ni * 16 + l15;
        float bc = bias[col];
#pragma unroll
        for (int mi = 0; mi < 2; ++mi) {
            int rb = mBase + wm * 32 + mi * 16 + lg * 4;
#pragma unroll
            for (int j = 0; j < 4; ++j) {
                float v = acc[mi][ni][j] + bc;
                if (act) v = v * 0.5f * (1.0f + erff(v * 0.7071067811865475f));
                C[(size_t)(rb + j) * N + col] = f2b(v);
            }
        }
    }
}

// ---------------------------------------------------------------------------
// MFMA flash attention, 8 waves (512 threads). Wave (wc,wn) owns chunks
// [wc*8, wc*8+8) x cols [wn*16, wn*16+16): halves the per-wave latency chain
// vs the 4-wave version. Partial-O per wave; single final LDS reduce.
// MODE 0: f32 RMW into avg. MODE 1: stream P bf16 to Pout.
#define PWST 40   // ushort stride per P row (80B, 16B-aligned)
#define NW 8
template <int MODE>
__global__ __launch_bounds__(512) void attn_fused(
    const ushort* __restrict__ qkv, const ushort* __restrict__ Vt,
    const float* __restrict__ bkTab, const float* __restrict__ bbTab,
    ushort* __restrict__ ctx, float* __restrict__ avg,
    ushort* __restrict__ Pout, int first) {
    __shared__ float bk_l[Ln];
    __shared__ float bb_l[Ln];
    __shared__ __align__(16) ushort Pw[NW][2][16 * PWST];  // [wave][hi/lo][i][k32]
    __shared__ float mm[NW][16];
    __shared__ float ll[NW][16];
    __shared__ float Opart[NW][1024];                      // [wave][d*16+i]

    int t = threadIdx.x;
    int lane = t & 63, w = t >> 6;        // w in [0,8)
    int wn = w & 3, wc = w >> 2;          // col slice, chunk half
    int l15 = lane & 15, lg = lane >> 4;

    int bid = blockIdx.x;
    int xcd = bid & 7, sub = bid >> 3;    // sub in [0,128)
    int bh = xcd * 2 + (sub >> 6);
    int q = sub & 63;
    int b = bh >> 2, hh = bh & 3;
    int i0 = q * 16;

#pragma unroll
    for (int ii = 0; ii < 2; ++ii) {
        bk_l[t + 512 * ii] = bkTab[hh * Ln + t + 512 * ii];
        bb_l[t + 512 * ii] = bbTab[hh * Ln + t + 512 * ii];
    }
    __syncthreads();

    // Q fragment (A-operand): row = i0 + l15, k = lg*8 (+32)
    bf16x8 qa0, qa1;
    {
        const ushort* qp = qkv + (size_t)(b * Ln + i0 + l15) * QKVW + hh * DKn;
        qa0 = *(const bf16x8*)(qp + lg * 8);
        qa1 = *(const bf16x8*)(qp + 32 + lg * 8);
    }

    const ushort* kbase = qkv + (size_t)(b * Ln) * QKVW + Dn + hh * DKn;

    // ---- QK pass over this wave's 8 chunks (barrier-free) -------------------
    f32x4 sv[8];
    float m[4] = {-1e30f, -1e30f, -1e30f, -1e30f};
#pragma unroll
    for (int cl = 0; cl < 8; ++cl) {
        int c = wc * 8 + cl;
        const ushort* kp = kbase + (size_t)(c * 64 + wn * 16 + l15) * QKVW;
        bf16x8 k0 = *(const bf16x8*)(kp + lg * 8);
        bf16x8 k1 = *(const bf16x8*)(kp + 32 + lg * 8);
        f32x4 acc = {};
        acc = __builtin_amdgcn_mfma_f32_16x16x32_bf16(qa0, k0, acc, 0, 0, 0);
        acc = __builtin_amdgcn_mfma_f32_16x16x32_bf16(qa1, k1, acc, 0, 0, 0);
        int j = c * 64 + wn * 16 + l15;
#pragma unroll
        for (int r = 0; r < 4; ++r) {
            int i = i0 + lg * 4 + r;
            int dist = (i > j) ? (i - j) : (j - i);
            float s = acc[r] * bk_l[dist] + bb_l[dist];
            sv[cl][r] = s;
            m[r] = fmaxf(m[r], s);
        }
    }
    // merge max over the 16 l15-lanes
#pragma unroll
    for (int mask = 1; mask < 16; mask <<= 1)
#pragma unroll
        for (int r = 0; r < 4; ++r) m[r] = fmaxf(m[r], __shfl_xor(m[r], mask, 64));
    // merge max across the 8 waves
    if (l15 == 0)
#pragma unroll
        for (int r = 0; r < 4; ++r) mm[w][lg * 4 + r] = m[r];
    __syncthreads();
#pragma unroll
    for (int r = 0; r < 4; ++r) {
        int row = lg * 4 + r;
        float m0 = fmaxf(fmaxf(mm[0][row], mm[1][row]), fmaxf(mm[2][row], mm[3][row]));
        float m1 = fmaxf(fmaxf(mm[4][row], mm[5][row]), fmaxf(mm[6][row], mm[7][row]));
        m[r] = fmaxf(m0, m1);
    }
    // p_unnorm = exp2(s - m); row sums
    float lsum[4] = {0.f, 0.f, 0.f, 0.f};
#pragma unroll
    for (int cl = 0; cl < 8; ++cl)
#pragma unroll
        for (int r = 0; r < 4; ++r) {
            float p = exp2f(sv[cl][r] - m[r]);
            sv[cl][r] = p;
            lsum[r] += p;
        }
#pragma unroll
    for (int mask = 1; mask < 16; mask <<= 1)
#pragma unroll
        for (int r = 0; r < 4; ++r) lsum[r] += __shfl_xor(lsum[r], mask, 64);
    if (l15 == 0)
#pragma unroll
        for (int r = 0; r < 4; ++r) ll[w][lg * 4 + r] = lsum[r];
    __syncthreads();
    float invl[4];
#pragma unroll
    for (int r = 0; r < 4; ++r) {
        int row = lg * 4 + r;
        invl[r] = 1.0f / (ll[0][row] + ll[1][row] + ll[2][row] + ll[3][row] +
                          ll[4][row] + ll[5][row] + ll[6][row] + ll[7][row]);
    }

    // ---- PV partial-O + P/avg output: ZERO barriers --------------------------
    const ushort* vbase = Vt + (size_t)bh * DKn * Ln;       // [64 d][Ln k]
    float* avgrow = avg + ((size_t)bh * Ln + i0) * Ln;      // MODE 0
    ushort* prow = Pout + ((size_t)bh * Ln + i0) * Ln;      // MODE 1
    int iw = lane >> 2, jq = lane & 3;                      // MODE 1 P-store map
    f32x4 acco[4] = {};
#pragma unroll
    for (int p = 0; p < 4; ++p) {
        const int c0 = wc * 8 + 2 * p, c1 = c0 + 1;
        float aold[2][4];
        if (MODE == 0 && !first) {
#pragma unroll
            for (int cc = 0; cc < 2; ++cc)
#pragma unroll
                for (int r = 0; r < 4; ++r)
                    aold[cc][r] = avgrow[(size_t)(lg * 4 + r) * Ln +
                                         (c0 + cc) * 64 + wn * 16 + l15];
        }
        // stage P (hi/lo) into wave-private LDS
#pragma unroll
        for (int cc = 0; cc < 2; ++cc)
#pragma unroll
            for (int r = 0; r < 4; ++r) {
                float pv = sv[2 * p + cc][r] * invl[r];
                sv[2 * p + cc][r] = pv;
                ushort ph = f2b(pv);
                int off = (lg * 4 + r) * PWST + cc * 16 + l15;
                Pw[w][0][off] = ph;
                Pw[w][1][off] = f2b(pv - b2f(ph));
            }
        // V A-fragments
        int kcol = (lg < 2 ? c0 : c1) * 64 + wn * 16 + (lg & 1) * 8;
        bf16x8 va0 = *(const bf16x8*)(vbase + (size_t)(0 * 16 + l15) * Ln + kcol);
        bf16x8 va1 = *(const bf16x8*)(vbase + (size_t)(1 * 16 + l15) * Ln + kcol);
        bf16x8 va2 = *(const bf16x8*)(vbase + (size_t)(2 * 16 + l15) * Ln + kcol);
        bf16x8 va3 = *(const bf16x8*)(vbase + (size_t)(3 * 16 + l15) * Ln + kcol);
        // B fragments from own LDS (same-wave RAW: compiler lgkmcnt)
        bf16x8 pbh = *(const bf16x8*)&Pw[w][0][l15 * PWST + lg * 8];
        bf16x8 pbl = *(const bf16x8*)&Pw[w][1][l15 * PWST + lg * 8];
        acco[0] = __builtin_amdgcn_mfma_f32_16x16x32_bf16(va0, pbh, acco[0], 0, 0, 0);
        acco[1] = __builtin_amdgcn_mfma_f32_16x16x32_bf16(va1, pbh, acco[1], 0, 0, 0);
        acco[2] = __builtin_amdgcn_mfma_f32_16x16x32_bf16(va2, pbh, acco[2], 0, 0, 0);
        acco[3] = __builtin_amdgcn_mfma_f32_16x16x32_bf16(va3, pbh, acco[3], 0, 0, 0);
        acco[0] = __builtin_amdgcn_mfma_f32_16x16x32_bf16(va0, pbl, acco[0], 0, 0, 0);
        acco[1] = __builtin_amdgcn_mfma_f32_16x16x32_bf16(va1, pbl, acco[1], 0, 0, 0);
        acco[2] = __builtin_amdgcn_mfma_f32_16x16x32_bf16(va2, pbl, acco[2], 0, 0, 0);
        acco[3] = __builtin_amdgcn_mfma_f32_16x16x32_bf16(va3, pbl, acco[3], 0, 0, 0);
        if (MODE == 0) {
#pragma unroll
            for (int cc = 0; cc < 2; ++cc)
#pragma unroll
                for (int r = 0; r < 4; ++r) {
                    float v = 0.25f * sv[2 * p + cc][r];
                    if (!first) v += aold[cc][r];
                    avgrow[(size_t)(lg * 4 + r) * Ln + (c0 + cc) * 64 + wn * 16 + l15] = v;
                }
        } else {
            ushort4 ph0 = *(const ushort4*)&Pw[w][0][iw * PWST + 0 * 16 + jq * 4];
            ushort4 ph1 = *(const ushort4*)&Pw[w][0][iw * PWST + 1 * 16 + jq * 4];
            *(ushort4*)&prow[(size_t)iw * Ln + c0 * 64 + wn * 16 + jq * 4] = ph0;
            *(ushort4*)&prow[(size_t)iw * Ln + c1 * 64 + wn * 16 + jq * 4] = ph1;
        }
    }

    // ---- reduce partial O across the 8 waves (single barrier) ---------------
#pragma unroll
    for (int dg = 0; dg < 4; ++dg)
#pragma unroll
        for (int r = 0; r < 4; ++r)
            Opart[w][(dg * 16 + lg * 4 + r) * 16 + l15] = acco[dg][r];
    __syncthreads();
#pragma unroll
    for (int k = 0; k < 2; ++k) {
        int idx = t + 512 * k;          // idx = d*16 + i
        float v = Opart[0][idx] + Opart[1][idx] + Opart[2][idx] + Opart[3][idx] +
                  Opart[4][idx] + Opart[5][idx] + Opart[6][idx] + Opart[7][idx];
        int dd = idx >> 4, ii = idx & 15;
        ctx[(size_t)(b * Ln + i0 + ii) * Dn + hh * DKn + dd] = f2b(v);
    }
}

// ---------------------------------------------------------------------------
// avg = 0.25 * (P0 + P1 + P2 + P3), pure streaming, 8 elems/thread (16B loads).
__global__ __launch_bounds__(256) void avg_sum_k(const ushort* __restrict__ P,
                                                 float* __restrict__ avg) {
    size_t e = ((size_t)blockIdx.x * 256 + threadIdx.x) * 8;
    uint4 a = *(const uint4*)&P[e];
    uint4 b4 = *(const uint4*)&P[(size_t)PELEMS + e];
    uint4 c4 = *(const uint4*)&P[(size_t)2 * PELEMS + e];
    uint4 d4 = *(const uint4*)&P[(size_t)3 * PELEMS + e];
    const ushort* ap = (const ushort*)&a;
    const ushort* bp = (const ushort*)&b4;
    const ushort* cp = (const ushort*)&c4;
    const ushort* dp = (const ushort*)&d4;
    float4 o0, o1;
    float* o0p = (float*)&o0;
    float* o1p = (float*)&o1;
#pragma unroll
    for (int k = 0; k < 4; ++k)
        o0p[k] = 0.25f * (b2f(ap[k]) + b2f(bp[k]) + b2f(cp[k]) + b2f(dp[k]));
#pragma unroll
    for (int k = 0; k < 4; ++k)
        o1p[k] = 0.25f * (b2f(ap[4 + k]) + b2f(bp[4 + k]) + b2f(cp[4 + k]) + b2f(dp[4 + k]));
    *(float4*)&avg[e] = o0;
    *(float4*)&avg[e + 4] = o1;
}

// ---------------------------------------------------------------------------
__global__ __launch_bounds__(256) void layernorm_k(const ushort* __restrict__ X,
                                                   const float* __restrict__ g,
                                                   const float* __restrict__ bta,
                                                   ushort* __restrict__ Y) {
    int w = threadIdx.x >> 6, lane = threadIdx.x & 63;
    int row = blockIdx.x * 4 + w;
    const ushort* xr = X + (size_t)row * Dn;
    float x[4];
#pragma unroll
    for (int ii = 0; ii < 4; ++ii) x[ii] = b2f(xr[lane + 64 * ii]);
    float s = x[0] + x[1] + x[2] + x[3];
#pragma unroll
    for (int m = 1; m < 64; m <<= 1) s += __shfl_xor(s, m, 64);
    float mu = s * (1.0f / 256.0f);
    float vs = 0.f;
#pragma unroll
    for (int ii = 0; ii < 4; ++ii) {
        float d = x[ii] - mu;
        vs += d * d;
    }
#pragma unroll
    for (int m = 1; m < 64; m <<= 1) vs += __shfl_xor(vs, m, 64);
    float rs = rsqrtf(vs * (1.0f / 256.0f) + 1e-5f);
#pragma unroll
    for (int ii = 0; ii < 4; ++ii) {
        int d = lane + 64 * ii;
        Y[(size_t)row * Dn + d] = f2b((x[ii] - mu) * rs * g[d] + bta[d]);
    }
}

// ---------------------------------------------------------------------------
__global__ __launch_bounds__(256) void mean_part_k(const ushort* __restrict__ Hb,
                                                   float* __restrict__ part) {
    int blk = blockIdx.x;            // 64 = 4 b x 16 groups
    int b = blk >> 4, g = blk & 15;
    int d = threadIdx.x;
    float s = 0.f;
#pragma unroll
    for (int r = 0; r < 64; ++r)
        s += b2f(Hb[(size_t)(b * Ln + g * 64 + r) * Dn + d]);
    part[(size_t)blk * Dn + d] = s;
}
__global__ __launch_bounds__(256) void mean_final_k(const float* __restrict__ part,
                                                    float* __restrict__ out) {
    int b = blockIdx.x, d = threadIdx.x;
    float s = 0.f;
#pragma unroll
    for (int g = 0; g < 16; ++g) s += part[(size_t)(b * 16 + g) * Dn + d];
    out[b * Dn + d] = s * (1.0f / (float)Ln);
}

// ---------------------------------------------------------------------------
extern "C" void kernel_launch(void* const* d_in, const int* in_sizes, int n_in,
                              void* d_out, int out_size, void* d_ws, size_t ws_size,
                              hipStream_t stream) {
    const float* x    = (const float*)d_in[0];
    const float* emb  = (const float*)d_in[1];
    const float* Wq   = (const float*)d_in[2];
    const float* bq   = (const float*)d_in[3];
    const float* Wk   = (const float*)d_in[4];
    const float* bk   = (const float*)d_in[5];
    const float* Wv   = (const float*)d_in[6];
    const float* bv   = (const float*)d_in[7];
    const float* Wo   = (const float*)d_in[8];
    const float* bo   = (const float*)d_in[9];
    const float* rk   = (const float*)d_in[10];
    const float* rb   = (const float*)d_in[11];
    const float* ln1g = (const float*)d_in[12];
    const float* ln1b = (const float*)d_in[13];
    const float* W1   = (const float*)d_in[14];
    const float* b1   = (const float*)d_in[15];
    const float* W2   = (const float*)d_in[16];
    const float* b2   = (const float*)d_in[17];
    const float* ln2g = (const float*)d_in[18];
    const float* ln2b = (const float*)d_in[19];

    float* out = (float*)d_out;
    float* avg = out + Bn * Dn;

    char* ws = (char*)d_ws;
    const size_t MB = 1024 * 1024;
    ushort* hb   = (ushort*)(ws);             // 2 MB
    ushort* qkvb = (ushort*)(ws + 2 * MB);    // 6 MB
    ushort* ctxb = (ushort*)(ws + 8 * MB);    // 2 MB
    ushort* t1   = (ushort*)(ws + 10 * MB);   // 2 MB
    ushort* ffb  = (ushort*)(ws + 12 * MB);   // 8 MB
    ushort* qkvT = (ushort*)(ws + 20 * MB);   // 1.5 MB
    ushort* WoT  = (ushort*)(ws + 22 * MB);   // 0.5 MB
    ushort* W1T  = (ushort*)(ws + 23 * MB);   // 2 MB
    ushort* W2T  = (ushort*)(ws + 25 * MB);   // 2 MB
    float*  bqkv = (float*)(ws + 27 * MB);
    float*  bkT  = (float*)(ws + 27 * MB + 65536);
    float*  bbT  = (float*)(ws + 27 * MB + 131072);
    ushort* Vt   = (ushort*)(ws + 30 * MB);   // 2 MB
    float*  mpart= (float*)(ws + 33 * MB);    // 64 KB
    ushort* Pbuf = (ushort*)(ws + 36 * MB);   // 4 x 32 MB (mode 1 only)

    const size_t need = 36 * MB + (size_t)4 * PELEMS * sizeof(ushort);
    const bool fancy = (ws_size >= need);

    embed_k<<<NTOK, 256, 0, stream>>>(x, emb, hb);
    relbias_k<<<64, 256, 0, stream>>>(rk, rb, bkT, bbT);
    prep_bias<<<12, 256, 0, stream>>>(bq, bk, bv, bqkv);

    dim3 t88(8, 8, NLn);
    transpose_cvt<<<t88, 256, 0, stream>>>(Wq, qkvT + 0,      256, 256, 65536, 196608);
    transpose_cvt<<<t88, 256, 0, stream>>>(Wk, qkvT + 65536,  256, 256, 65536, 196608);
    transpose_cvt<<<t88, 256, 0, stream>>>(Wv, qkvT + 131072, 256, 256, 65536, 196608);
    transpose_cvt<<<t88, 256, 0, stream>>>(Wo, WoT,           256, 256, 65536, 65536);
    transpose_cvt<<<dim3(32, 8, NLn), 256, 0, stream>>>(W1, W1T, 256, 1024, 262144, 262144);
    transpose_cvt<<<dim3(8, 32, NLn), 256, 0, stream>>>(W2, W2T, 1024, 256, 262144, 262144);

    for (int l = 0; l < NLn; ++l) {
        gemm_mfma<<<dim3(12, 64), 256, 0, stream>>>(
            hb, qkvT + (size_t)l * 196608, bqkv + l * QKVW, qkvb, NTOK, QKVW, Dn, 0);
        transpose_v<<<dim3(32, 16), 256, 0, stream>>>(qkvb, Vt);
        if (fancy) {
            attn_fused<1><<<1024, 512, 0, stream>>>(
                qkvb, Vt, bkT + l * Hn * Ln, bbT + l * Hn * Ln, ctxb, avg,
                Pbuf + (size_t)l * PELEMS, (l == 0) ? 1 : 0);
        } else {
            attn_fused<0><<<1024, 512, 0, stream>>>(
                qkvb, Vt, bkT + l * Hn * Ln, bbT + l * Hn * Ln, ctxb, avg,
                (ushort*)Pbuf, (l == 0) ? 1 : 0);
        }
        gemm_mfma<<<dim3(4, 64), 256, 0, stream>>>(
            ctxb, WoT + (size_t)l * 65536, bo + l * 256, t1, NTOK, Dn, Dn, 0);
        layernorm_k<<<NTOK / 4, 256, 0, stream>>>(
            t1, ln1g + l * 256, ln1b + l * 256, t1);
        gemm_mfma<<<dim3(16, 64), 256, 0, stream>>>(
            t1, W1T + (size_t)l * 262144, b1 + l * FFn, ffb, NTOK, FFn, Dn, 1);
        gemm_mfma<<<dim3(4, 64), 256, 0, stream>>>(
            ffb, W2T + (size_t)l * 262144, b2 + l * 256, hb, NTOK, Dn, FFn, 0);
        layernorm_k<<<NTOK / 4, 256, 0, stream>>>(
            hb, ln2g + l * 256, ln2b + l * 256, hb);
    }
    if (fancy) {
        avg_sum_k<<<PELEMS / (256 * 8), 256, 0, stream>>>(Pbuf, avg);
    }
    mean_part_k<<<64, 256, 0, stream>>>(hb, mpart);
    mean_final_k<<<Bn, 256, 0, stream>>>(mpart, out);
}

// Round 11
// 416.137 us; speedup vs baseline: 1.0246x; 1.0076x over previous
//
#include <hip/hip_runtime.h>
#include <hip/hip_bf16.h>
#include <math.h>

// Problem constants
#define Bn 4
#define Ln 1024
#define Vn 64
#define Dn 256
#define Hn 4
#define DKn 64
#define NLn 4
#define Mn 20
#define FFn 1024
#define NTOK (Bn * Ln)   // 4096
#define QKVW 768         // fused q|k|v width
#define LOG2E 1.4426950408889634f
#define PELEMS (Bn * Hn * Ln * Ln)   // 16777216 elements per layer P

typedef __attribute__((ext_vector_type(8))) short bf16x8;
typedef __attribute__((ext_vector_type(4))) float f32x4;

__device__ __forceinline__ ushort f2b(float f) {   // fp32 -> bf16 RNE
    uint u = __float_as_uint(f);
    u += 0x7fff + ((u >> 16) & 1);
    return (ushort)(u >> 16);
}
__device__ __forceinline__ float b2f(ushort u) {   // exact
    return __uint_as_float(((uint)u) << 16);
}

// ---------------------------------------------------------------------------
__global__ __launch_bounds__(256) void embed_k(const float* __restrict__ X,
                                               const float* __restrict__ E,
                                               ushort* __restrict__ Hb) {
    __shared__ float xs[Vn];
    int n = blockIdx.x, d = threadIdx.x;
    if (threadIdx.x < Vn) xs[threadIdx.x] = X[n * Vn + threadIdx.x];
    __syncthreads();
    float s = 0.f;
#pragma unroll
    for (int v = 0; v < Vn; ++v) s += xs[v] * E[v * Dn + d];
    Hb[(size_t)n * Dn + d] = f2b(s);
}

// ---------------------------------------------------------------------------
// bias tables, pre-scaled into exp2 domain
__global__ __launch_bounds__(256) void relbias_k(const float* __restrict__ rk,
                                                 const float* __restrict__ rb,
                                                 float* __restrict__ bkT,
                                                 float* __restrict__ bbT) {
    int tid = blockIdx.x * 256 + threadIdx.x;   // < NL*H*1024
    int dist = tid & 1023;
    int hh = (tid >> 10) & 3;
    int l = tid >> 12;
    float dd = (float)dist;
    if (dist > Mn) dd = (float)Mn + log2f((float)(dist - Mn));
    if (dd > 2.0f * Mn) dd = 2.0f * Mn;
    int idx = (int)dd;
    bkT[tid] = rk[(l * (2 * Mn + 1) + idx) * Hn + hh] * 0.125f * LOG2E;
    bbT[tid] = rb[(l * (2 * Mn + 1) + idx) * Hn + hh] * LOG2E;
}

// ---------------------------------------------------------------------------
__global__ __launch_bounds__(256) void prep_bias(const float* __restrict__ bq,
                                                 const float* __restrict__ bk,
                                                 const float* __restrict__ bv,
                                                 float* __restrict__ bqkv) {
    int idx = blockIdx.x * 256 + threadIdx.x;   // < NL*768
    int l = idx / QKVW, r = idx - l * QKVW;
    float v;
    if (r < 256)      v = bq[l * 256 + r];
    else if (r < 512) v = bk[l * 256 + r - 256];
    else              v = bv[l * 256 + r - 512];
    bqkv[idx] = v;
}

// ---------------------------------------------------------------------------
// Weight transpose + fp32->bf16: dst[c][r] = src[r][c]; grid.z = layer.
__global__ __launch_bounds__(256) void transpose_cvt(
    const float* __restrict__ src, ushort* __restrict__ dst,
    int R, int C, int srcLS, int dstLS) {
    __shared__ float s[32][33];
    src += (size_t)blockIdx.z * srcLS;
    dst += (size_t)blockIdx.z * dstLS;
    int r0 = blockIdx.y * 32, c0 = blockIdx.x * 32;
    int tx = threadIdx.x & 31, ty = threadIdx.x >> 5;
#pragma unroll
    for (int ii = 0; ii < 4; ++ii)
        s[ty + 8 * ii][tx] = src[(size_t)(r0 + ty + 8 * ii) * C + c0 + tx];
    __syncthreads();
#pragma unroll
    for (int ii = 0; ii < 4; ++ii)
        dst[(size_t)(c0 + ty + 8 * ii) * R + r0 + tx] = f2b(s[tx][ty + 8 * ii]);
}

// ---------------------------------------------------------------------------
// V transpose per (b,h): Vt[bh][d][j] = qkvb[b*L+j][512 + h*64 + d]
__global__ __launch_bounds__(256) void transpose_v(const ushort* __restrict__ qkv,
                                                   ushort* __restrict__ Vt) {
    __shared__ ushort s[32][65];
    int j0 = blockIdx.x * 32;
    int bh = blockIdx.y;
    int b = bh >> 2, hh = bh & 3;
    int t = threadIdx.x;
#pragma unroll
    for (int ii = 0; ii < 8; ++ii) {
        int e = t + 256 * ii;          // 2048 = 32 j x 64 d
        int jr = e >> 6, dc = e & 63;
        s[jr][dc] = qkv[(size_t)(b * Ln + j0 + jr) * QKVW + 2 * Dn + hh * DKn + dc];
    }
    __syncthreads();
#pragma unroll
    for (int ii = 0; ii < 8; ++ii) {
        int e = t + 256 * ii;          // 2048 = 64 d x 32 j
        int dr = e >> 5, jc = e & 31;
        Vt[(size_t)(bh * DKn + dr) * Ln + j0 + jc] = s[jc][dr];
    }
}

// ---------------------------------------------------------------------------
// bf16 MFMA GEMM: C[m][n] = act(sum_k LN?(A)[m][k]*Bt[n][k] + bias[n]), C bf16.
// LNA=1: LayerNorm(A row) fused into the A staging (requires K==256).
#define GST 40
#define GEMM_FRAG_MFMA                                                        \
    bf16x8 a0 = *(const bf16x8*)&As[(wm * 32 + l15) * GST + lg * 8];          \
    bf16x8 a1 = *(const bf16x8*)&As[(wm * 32 + 16 + l15) * GST + lg * 8];     \
    bf16x8 b0 = *(const bf16x8*)&Bs[(wn * 32 + l15) * GST + lg * 8];          \
    bf16x8 b1 = *(const bf16x8*)&Bs[(wn * 32 + 16 + l15) * GST + lg * 8];     \
    acc[0][0] = __builtin_amdgcn_mfma_f32_16x16x32_bf16(a0, b0, acc[0][0], 0, 0, 0); \
    acc[0][1] = __builtin_amdgcn_mfma_f32_16x16x32_bf16(a0, b1, acc[0][1], 0, 0, 0); \
    acc[1][0] = __builtin_amdgcn_mfma_f32_16x16x32_bf16(a1, b0, acc[1][0], 0, 0, 0); \
    acc[1][1] = __builtin_amdgcn_mfma_f32_16x16x32_bf16(a1, b1, acc[1][1], 0, 0, 0);

template <int LNA>
__global__ __launch_bounds__(256) void gemm_mfma(
    const ushort* __restrict__ A, const ushort* __restrict__ Bt,
    const float* __restrict__ bias, ushort* __restrict__ C,
    int M, int N, int K, int act,
    const float* __restrict__ lng, const float* __restrict__ lnb) {
    __shared__ __align__(16) ushort As[64 * GST];
    __shared__ __align__(16) ushort Bs[64 * GST];
    __shared__ float gl[256];
    __shared__ float bl[256];
    int t = threadIdx.x;
    int lane = t & 63, w = t >> 6;
    int wm = w >> 1, wn = w & 1;
    int l15 = lane & 15, lg = lane >> 4;
    int mBase = blockIdx.y * 64, nBase = blockIdx.x * 64;
    int lrow = t >> 2, lkc = (t & 3) * 8;
    const ushort* Ap = A + (size_t)(mBase + lrow) * K + lkc;
    const ushort* Bp = Bt + (size_t)(nBase + lrow) * K + lkc;
    f32x4 acc[2][2] = {};

    if constexpr (LNA) {
        // K == 256. Preload full A row slice, compute LN stats over 4 lanes.
        uint4 areg[8];
        float s = 0.f;
#pragma unroll
        for (int kc = 0; kc < 8; ++kc) {
            areg[kc] = *(const uint4*)(Ap + kc * 32);
            const ushort* e = (const ushort*)&areg[kc];
#pragma unroll
            for (int q = 0; q < 8; ++q) s += b2f(e[q]);
        }
        s += __shfl_xor(s, 1, 64);
        s += __shfl_xor(s, 2, 64);
        float mu = s * (1.0f / 256.0f);
        float vv = 0.f;
#pragma unroll
        for (int kc = 0; kc < 8; ++kc) {
            const ushort* e = (const ushort*)&areg[kc];
#pragma unroll
            for (int q = 0; q < 8; ++q) {
                float d = b2f(e[q]) - mu;
                vv += d * d;
            }
        }
        vv += __shfl_xor(vv, 1, 64);
        vv += __shfl_xor(vv, 2, 64);
        float rs = rsqrtf(vv * (1.0f / 256.0f) + 1e-5f);
        gl[t] = lng[t];
        bl[t] = lnb[t];
        __syncthreads();   // gl/bl visible
#pragma unroll
        for (int kc = 0; kc < 8; ++kc) {
            uint4 bv = *(const uint4*)(Bp + kc * 32);
            __syncthreads();   // prior fragment reads done
            {
                const ushort* e = (const ushort*)&areg[kc];
                ushort outv[8];
#pragma unroll
                for (int q = 0; q < 8; ++q) {
                    int col = kc * 32 + lkc + q;
                    outv[q] = f2b((b2f(e[q]) - mu) * rs * gl[col] + bl[col]);
                }
                *(uint4*)&As[lrow * GST + lkc] = *(const uint4*)outv;
            }
            *(uint4*)&Bs[lrow * GST + lkc] = bv;
            __syncthreads();
            GEMM_FRAG_MFMA
        }
    } else {
        for (int k0 = 0; k0 < K; k0 += 32) {
            uint4 av = *(const uint4*)(Ap + k0);
            uint4 bv = *(const uint4*)(Bp + k0);
            __syncthreads();
            *(uint4*)&As[lrow * GST + lkc] = av;
            *(uint4*)&Bs[lrow * GST + lkc] = bv;
            __syncthreads();
            GEMM_FRAG_MFMA
        }
    }
#pragma unroll
    for (int ni = 0; ni < 2; ++ni) {
        int col = nBase + wn * 32 + ni * 16 + l15;
        float bc = bias[col];
#pragma unroll
        for (int mi = 0; mi < 2; ++mi) {
            int rb = mBase + wm * 32 + mi * 16 + lg * 4;
#pragma unroll
            for (int j = 0; j < 4; ++j) {
                float v = acc[mi][ni][j] + bc;
                if (act) v = v * 0.5f * (1.0f + erff(v * 0.7071067811865475f));
                C[(size_t)(rb + j) * N + col] = f2b(v);
            }
        }
    }
}

// ---------------------------------------------------------------------------
// MFMA flash attention, 8 waves. Wave-private LDS: Pw (PV staging) and Opart
// (final reduce) are UNIONED (never live simultaneously per wave) -> LDS 41KB
// -> 3 blocks/CU. MODE 0: f32 RMW into avg. MODE 1: stream P bf16 to Pout.
#define PWST 40   // ushort stride per P row (80B, 16B-aligned)
#define NW 8
template <int MODE>
__global__ __launch_bounds__(512) void attn_fused(
    const ushort* __restrict__ qkv, const ushort* __restrict__ Vt,
    const float* __restrict__ bkTab, const float* __restrict__ bbTab,
    ushort* __restrict__ ctx, float* __restrict__ avg,
    ushort* __restrict__ Pout, int first) {
    __shared__ float bk_l[Ln];
    __shared__ float bb_l[Ln];
    __shared__ __align__(16) char uni[NW][4096];   // Pw (2560B) / Opart (4096B)
    __shared__ float mm[NW][16];
    __shared__ float ll[NW][16];

    int t = threadIdx.x;
    int lane = t & 63, w = t >> 6;        // w in [0,8)
    int wn = w & 3, wc = w >> 2;          // col slice, chunk half
    int l15 = lane & 15, lg = lane >> 4;

    ushort* pwh = (ushort*)&uni[w][0];     // [16*PWST] P hi
    ushort* pwl = (ushort*)&uni[w][1280];  // [16*PWST] P lo

    int bid = blockIdx.x;
    int xcd = bid & 7, sub = bid >> 3;    // sub in [0,128)
    int bh = xcd * 2 + (sub >> 6);
    int q = sub & 63;
    int b = bh >> 2, hh = bh & 3;
    int i0 = q * 16;

#pragma unroll
    for (int ii = 0; ii < 2; ++ii) {
        bk_l[t + 512 * ii] = bkTab[hh * Ln + t + 512 * ii];
        bb_l[t + 512 * ii] = bbTab[hh * Ln + t + 512 * ii];
    }
    __syncthreads();

    // Q fragment (A-operand): row = i0 + l15, k = lg*8 (+32)
    bf16x8 qa0, qa1;
    {
        const ushort* qp = qkv + (size_t)(b * Ln + i0 + l15) * QKVW + hh * DKn;
        qa0 = *(const bf16x8*)(qp + lg * 8);
        qa1 = *(const bf16x8*)(qp + 32 + lg * 8);
    }

    const ushort* kbase = qkv + (size_t)(b * Ln) * QKVW + Dn + hh * DKn;

    // ---- QK pass over this wave's 8 chunks (barrier-free) -------------------
    f32x4 sv[8];
    float m[4] = {-1e30f, -1e30f, -1e30f, -1e30f};
#pragma unroll
    for (int cl = 0; cl < 8; ++cl) {
        int c = wc * 8 + cl;
        const ushort* kp = kbase + (size_t)(c * 64 + wn * 16 + l15) * QKVW;
        bf16x8 k0 = *(const bf16x8*)(kp + lg * 8);
        bf16x8 k1 = *(const bf16x8*)(kp + 32 + lg * 8);
        f32x4 acc = {};
        acc = __builtin_amdgcn_mfma_f32_16x16x32_bf16(qa0, k0, acc, 0, 0, 0);
        acc = __builtin_amdgcn_mfma_f32_16x16x32_bf16(qa1, k1, acc, 0, 0, 0);
        int j = c * 64 + wn * 16 + l15;
#pragma unroll
        for (int r = 0; r < 4; ++r) {
            int i = i0 + lg * 4 + r;
            int dist = (i > j) ? (i - j) : (j - i);
            float s = acc[r] * bk_l[dist] + bb_l[dist];
            sv[cl][r] = s;
            m[r] = fmaxf(m[r], s);
        }
    }
    // merge max over the 16 l15-lanes
#pragma unroll
    for (int mask = 1; mask < 16; mask <<= 1)
#pragma unroll
        for (int r = 0; r < 4; ++r) m[r] = fmaxf(m[r], __shfl_xor(m[r], mask, 64));
    // merge max across the 8 waves
    if (l15 == 0)
#pragma unroll
        for (int r = 0; r < 4; ++r) mm[w][lg * 4 + r] = m[r];
    __syncthreads();
#pragma unroll
    for (int r = 0; r < 4; ++r) {
        int row = lg * 4 + r;
        float m0 = fmaxf(fmaxf(mm[0][row], mm[1][row]), fmaxf(mm[2][row], mm[3][row]));
        float m1 = fmaxf(fmaxf(mm[4][row], mm[5][row]), fmaxf(mm[6][row], mm[7][row]));
        m[r] = fmaxf(m0, m1);
    }
    // p_unnorm = exp2(s - m); row sums
    float lsum[4] = {0.f, 0.f, 0.f, 0.f};
#pragma unroll
    for (int cl = 0; cl < 8; ++cl)
#pragma unroll
        for (int r = 0; r < 4; ++r) {
            float p = exp2f(sv[cl][r] - m[r]);
            sv[cl][r] = p;
            lsum[r] += p;
        }
#pragma unroll
    for (int mask = 1; mask < 16; mask <<= 1)
#pragma unroll
        for (int r = 0; r < 4; ++r) lsum[r] += __shfl_xor(lsum[r], mask, 64);
    if (l15 == 0)
#pragma unroll
        for (int r = 0; r < 4; ++r) ll[w][lg * 4 + r] = lsum[r];
    __syncthreads();
    float invl[4];
#pragma unroll
    for (int r = 0; r < 4; ++r) {
        int row = lg * 4 + r;
        invl[r] = 1.0f / (ll[0][row] + ll[1][row] + ll[2][row] + ll[3][row] +
                          ll[4][row] + ll[5][row] + ll[6][row] + ll[7][row]);
    }

    // ---- PV partial-O + P/avg output: ZERO barriers --------------------------
    const ushort* vbase = Vt + (size_t)bh * DKn * Ln;       // [64 d][Ln k]
    float* avgrow = avg + ((size_t)bh * Ln + i0) * Ln;      // MODE 0
    ushort* prow = Pout + ((size_t)bh * Ln + i0) * Ln;      // MODE 1
    int iw = lane >> 2, jq = lane & 3;                      // MODE 1 P-store map
    f32x4 acco[4] = {};
#pragma unroll
    for (int p = 0; p < 4; ++p) {
        const int c0 = wc * 8 + 2 * p, c1 = c0 + 1;
        float aold[2][4];
        if (MODE == 0 && !first) {
#pragma unroll
            for (int cc = 0; cc < 2; ++cc)
#pragma unroll
                for (int r = 0; r < 4; ++r)
                    aold[cc][r] = avgrow[(size_t)(lg * 4 + r) * Ln +
                                         (c0 + cc) * 64 + wn * 16 + l15];
        }
        // stage P (hi/lo) into wave-private LDS
#pragma unroll
        for (int cc = 0; cc < 2; ++cc)
#pragma unroll
            for (int r = 0; r < 4; ++r) {
                float pv = sv[2 * p + cc][r] * invl[r];
                sv[2 * p + cc][r] = pv;
                ushort ph = f2b(pv);
                int off = (lg * 4 + r) * PWST + cc * 16 + l15;
                pwh[off] = ph;
                pwl[off] = f2b(pv - b2f(ph));
            }
        // V A-fragments
        int kcol = (lg < 2 ? c0 : c1) * 64 + wn * 16 + (lg & 1) * 8;
        bf16x8 va0 = *(const bf16x8*)(vbase + (size_t)(0 * 16 + l15) * Ln + kcol);
        bf16x8 va1 = *(const bf16x8*)(vbase + (size_t)(1 * 16 + l15) * Ln + kcol);
        bf16x8 va2 = *(const bf16x8*)(vbase + (size_t)(2 * 16 + l15) * Ln + kcol);
        bf16x8 va3 = *(const bf16x8*)(vbase + (size_t)(3 * 16 + l15) * Ln + kcol);
        // B fragments from own LDS (same-wave RAW: compiler lgkmcnt)
        bf16x8 pbh = *(const bf16x8*)&pwh[l15 * PWST + lg * 8];
        bf16x8 pbl = *(const bf16x8*)&pwl[l15 * PWST + lg * 8];
        acco[0] = __builtin_amdgcn_mfma_f32_16x16x32_bf16(va0, pbh, acco[0], 0, 0, 0);
        acco[1] = __builtin_amdgcn_mfma_f32_16x16x32_bf16(va1, pbh, acco[1], 0, 0, 0);
        acco[2] = __builtin_amdgcn_mfma_f32_16x16x32_bf16(va2, pbh, acco[2], 0, 0, 0);
        acco[3] = __builtin_amdgcn_mfma_f32_16x16x32_bf16(va3, pbh, acco[3], 0, 0, 0);
        acco[0] = __builtin_amdgcn_mfma_f32_16x16x32_bf16(va0, pbl, acco[0], 0, 0, 0);
        acco[1] = __builtin_amdgcn_mfma_f32_16x16x32_bf16(va1, pbl, acco[1], 0, 0, 0);
        acco[2] = __builtin_amdgcn_mfma_f32_16x16x32_bf16(va2, pbl, acco[2], 0, 0, 0);
        acco[3] = __builtin_amdgcn_mfma_f32_16x16x32_bf16(va3, pbl, acco[3], 0, 0, 0);
        if (MODE == 0) {
#pragma unroll
            for (int cc = 0; cc < 2; ++cc)
#pragma unroll
                for (int r = 0; r < 4; ++r) {
                    float v = 0.25f * sv[2 * p + cc][r];
                    if (!first) v += aold[cc][r];
                    avgrow[(size_t)(lg * 4 + r) * Ln + (c0 + cc) * 64 + wn * 16 + l15] = v;
                }
        } else {
            ushort4 ph0 = *(const ushort4*)&pwh[iw * PWST + 0 * 16 + jq * 4];
            ushort4 ph1 = *(const ushort4*)&pwh[iw * PWST + 1 * 16 + jq * 4];
            *(ushort4*)&prow[(size_t)iw * Ln + c0 * 64 + wn * 16 + jq * 4] = ph0;
            *(ushort4*)&prow[(size_t)iw * Ln + c1 * 64 + wn * 16 + jq * 4] = ph1;
        }
    }

    // ---- reduce partial O across the 8 waves (Opart unions over Pw) ----------
    // Safe: Opart stores' data depends on the final MFMAs, which consumed the
    // last pwh/pwl reads (in-order LDS per wave).
    {
        float* op = (float*)&uni[w][0];
#pragma unroll
        for (int dg = 0; dg < 4; ++dg)
#pragma unroll
            for (int r = 0; r < 4; ++r)
                op[(dg * 16 + lg * 4 + r) * 16 + l15] = acco[dg][r];
    }
    __syncthreads();
#pragma unroll
    for (int k = 0; k < 2; ++k) {
        int idx = t + 512 * k;          // idx = d*16 + i
        float v = 0.f;
#pragma unroll
        for (int wv = 0; wv < NW; ++wv) v += ((const float*)&uni[wv][0])[idx];
        int dd = idx >> 4, ii = idx & 15;
        ctx[(size_t)(b * Ln + i0 + ii) * Dn + hh * DKn + dd] = f2b(v);
    }
}

// ---------------------------------------------------------------------------
// avg = 0.25 * (P0 + P1 + P2 + P3), pure streaming, 8 elems/thread (16B loads).
__global__ __launch_bounds__(256) void avg_sum_k(const ushort* __restrict__ P,
                                                 float* __restrict__ avg) {
    size_t e = ((size_t)blockIdx.x * 256 + threadIdx.x) * 8;
    uint4 a = *(const uint4*)&P[e];
    uint4 b4 = *(const uint4*)&P[(size_t)PELEMS + e];
    uint4 c4 = *(const uint4*)&P[(size_t)2 * PELEMS + e];
    uint4 d4 = *(const uint4*)&P[(size_t)3 * PELEMS + e];
    const ushort* ap = (const ushort*)&a;
    const ushort* bp = (const ushort*)&b4;
    const ushort* cp = (const ushort*)&c4;
    const ushort* dp = (const ushort*)&d4;
    float4 o0, o1;
    float* o0p = (float*)&o0;
    float* o1p = (float*)&o1;
#pragma unroll
    for (int k = 0; k < 4; ++k)
        o0p[k] = 0.25f * (b2f(ap[k]) + b2f(bp[k]) + b2f(cp[k]) + b2f(dp[k]));
#pragma unroll
    for (int k = 0; k < 4; ++k)
        o1p[k] = 0.25f * (b2f(ap[4 + k]) + b2f(bp[4 + k]) + b2f(cp[4 + k]) + b2f(dp[4 + k]));
    *(float4*)&avg[e] = o0;
    *(float4*)&avg[e + 4] = o1;
}

// ---------------------------------------------------------------------------
__global__ __launch_bounds__(256) void layernorm_k(const ushort* __restrict__ X,
                                                   const float* __restrict__ g,
                                                   const float* __restrict__ bta,
                                                   ushort* __restrict__ Y) {
    int w = threadIdx.x >> 6, lane = threadIdx.x & 63;
    int row = blockIdx.x * 4 + w;
    const ushort* xr = X + (size_t)row * Dn;
    float x[4];
#pragma unroll
    for (int ii = 0; ii < 4; ++ii) x[ii] = b2f(xr[lane + 64 * ii]);
    float s = x[0] + x[1] + x[2] + x[3];
#pragma unroll
    for (int m = 1; m < 64; m <<= 1) s += __shfl_xor(s, m, 64);
    float mu = s * (1.0f / 256.0f);
    float vs = 0.f;
#pragma unroll
    for (int ii = 0; ii < 4; ++ii) {
        float d = x[ii] - mu;
        vs += d * d;
    }
#pragma unroll
    for (int m = 1; m < 64; m <<= 1) vs += __shfl_xor(vs, m, 64);
    float rs = rsqrtf(vs * (1.0f / 256.0f) + 1e-5f);
#pragma unroll
    for (int ii = 0; ii < 4; ++ii) {
        int d = lane + 64 * ii;
        Y[(size_t)row * Dn + d] = f2b((x[ii] - mu) * rs * g[d] + bta[d]);
    }
}

// ---------------------------------------------------------------------------
__global__ __launch_bounds__(256) void mean_part_k(const ushort* __restrict__ Hb,
                                                   float* __restrict__ part) {
    int blk = blockIdx.x;            // 64 = 4 b x 16 groups
    int b = blk >> 4, g = blk & 15;
    int d = threadIdx.x;
    float s = 0.f;
#pragma unroll
    for (int r = 0; r < 64; ++r)
        s += b2f(Hb[(size_t)(b * Ln + g * 64 + r) * Dn + d]);
    part[(size_t)blk * Dn + d] = s;
}
__global__ __launch_bounds__(256) void mean_final_k(const float* __restrict__ part,
                                                    float* __restrict__ out) {
    int b = blockIdx.x, d = threadIdx.x;
    float s = 0.f;
#pragma unroll
    for (int g = 0; g < 16; ++g) s += part[(size_t)(b * 16 + g) * Dn + d];
    out[b * Dn + d] = s * (1.0f / (float)Ln);
}

// ---------------------------------------------------------------------------
extern "C" void kernel_launch(void* const* d_in, const int* in_sizes, int n_in,
                              void* d_out, int out_size, void* d_ws, size_t ws_size,
                              hipStream_t stream) {
    const float* x    = (const float*)d_in[0];
    const float* emb  = (const float*)d_in[1];
    const float* Wq   = (const float*)d_in[2];
    const float* bq   = (const float*)d_in[3];
    const float* Wk   = (const float*)d_in[4];
    const float* bk   = (const float*)d_in[5];
    const float* Wv   = (const float*)d_in[6];
    const float* bv   = (const float*)d_in[7];
    const float* Wo   = (const float*)d_in[8];
    const float* bo   = (const float*)d_in[9];
    const float* rk   = (const float*)d_in[10];
    const float* rb   = (const float*)d_in[11];
    const float* ln1g = (const float*)d_in[12];
    const float* ln1b = (const float*)d_in[13];
    const float* W1   = (const float*)d_in[14];
    const float* b1   = (const float*)d_in[15];
    const float* W2   = (const float*)d_in[16];
    const float* b2   = (const float*)d_in[17];
    const float* ln2g = (const float*)d_in[18];
    const float* ln2b = (const float*)d_in[19];

    float* out = (float*)d_out;
    float* avg = out + Bn * Dn;

    char* ws = (char*)d_ws;
    const size_t MB = 1024 * 1024;
    ushort* hb   = (ushort*)(ws);             // 2 MB
    ushort* qkvb = (ushort*)(ws + 2 * MB);    // 6 MB
    ushort* ctxb = (ushort*)(ws + 8 * MB);    // 2 MB
    ushort* t1   = (ushort*)(ws + 10 * MB);   // 2 MB
    ushort* ffb  = (ushort*)(ws + 12 * MB);   // 8 MB
    ushort* qkvT = (ushort*)(ws + 20 * MB);   // 1.5 MB
    ushort* WoT  = (ushort*)(ws + 22 * MB);   // 0.5 MB
    ushort* W1T  = (ushort*)(ws + 23 * MB);   // 2 MB
    ushort* W2T  = (ushort*)(ws + 25 * MB);   // 2 MB
    float*  bqkv = (float*)(ws + 27 * MB);
    float*  bkT  = (float*)(ws + 27 * MB + 65536);
    float*  bbT  = (float*)(ws + 27 * MB + 131072);
    ushort* Vt   = (ushort*)(ws + 30 * MB);   // 2 MB
    float*  mpart= (float*)(ws + 33 * MB);    // 64 KB
    ushort* Pbuf = (ushort*)(ws + 36 * MB);   // 4 x 32 MB (mode 1 only)

    const size_t need = 36 * MB + (size_t)4 * PELEMS * sizeof(ushort);
    const bool fancy = (ws_size >= need);

    embed_k<<<NTOK, 256, 0, stream>>>(x, emb, hb);
    relbias_k<<<64, 256, 0, stream>>>(rk, rb, bkT, bbT);
    prep_bias<<<12, 256, 0, stream>>>(bq, bk, bv, bqkv);

    dim3 t88(8, 8, NLn);
    transpose_cvt<<<t88, 256, 0, stream>>>(Wq, qkvT + 0,      256, 256, 65536, 196608);
    transpose_cvt<<<t88, 256, 0, stream>>>(Wk, qkvT + 65536,  256, 256, 65536, 196608);
    transpose_cvt<<<t88, 256, 0, stream>>>(Wv, qkvT + 131072, 256, 256, 65536, 196608);
    transpose_cvt<<<t88, 256, 0, stream>>>(Wo, WoT,           256, 256, 65536, 65536);
    transpose_cvt<<<dim3(32, 8, NLn), 256, 0, stream>>>(W1, W1T, 256, 1024, 262144, 262144);
    transpose_cvt<<<dim3(8, 32, NLn), 256, 0, stream>>>(W2, W2T, 1024, 256, 262144, 262144);

    for (int l = 0; l < NLn; ++l) {
        // QKV projection; layers 1..3 fuse ln2 of the previous layer into A.
        if (l == 0) {
            gemm_mfma<0><<<dim3(12, 64), 256, 0, stream>>>(
                hb, qkvT + (size_t)l * 196608, bqkv + l * QKVW, qkvb,
                NTOK, QKVW, Dn, 0, nullptr, nullptr);
        } else {
            gemm_mfma<1><<<dim3(12, 64), 256, 0, stream>>>(
                hb, qkvT + (size_t)l * 196608, bqkv + l * QKVW, qkvb,
                NTOK, QKVW, Dn, 0, ln2g + (l - 1) * 256, ln2b + (l - 1) * 256);
        }
        transpose_v<<<dim3(32, 16), 256, 0, stream>>>(qkvb, Vt);
        if (fancy) {
            attn_fused<1><<<1024, 512, 0, stream>>>(
                qkvb, Vt, bkT + l * Hn * Ln, bbT + l * Hn * Ln, ctxb, avg,
                Pbuf + (size_t)l * PELEMS, (l == 0) ? 1 : 0);
        } else {
            attn_fused<0><<<1024, 512, 0, stream>>>(
                qkvb, Vt, bkT + l * Hn * Ln, bbT + l * Hn * Ln, ctxb, avg,
                (ushort*)Pbuf, (l == 0) ? 1 : 0);
        }
        gemm_mfma<0><<<dim3(4, 64), 256, 0, stream>>>(
            ctxb, WoT + (size_t)l * 65536, bo + l * 256, t1,
            NTOK, Dn, Dn, 0, nullptr, nullptr);
        // FF1 with fused ln1 + exact GELU
        gemm_mfma<1><<<dim3(16, 64), 256, 0, stream>>>(
            t1, W1T + (size_t)l * 262144, b1 + l * FFn, ffb,
            NTOK, FFn, Dn, 1, ln1g + l * 256, ln1b + l * 256);
        gemm_mfma<0><<<dim3(4, 64), 256, 0, stream>>>(
            ffb, W2T + (size_t)l * 262144, b2 + l * 256, hb,
            NTOK, Dn, FFn, 0, nullptr, nullptr);
    }
    // final ln2 (layer 3) before the mean
    layernorm_k<<<NTOK / 4, 256, 0, stream>>>(
        hb, ln2g + 3 * 256, ln2b + 3 * 256, hb);
    if (fancy) {
        avg_sum_k<<<PELEMS / (256 * 8), 256, 0, stream>>>(Pbuf, avg);
    }
    mean_part_k<<<64, 256, 0, stream>>>(hb, mpart);
    mean_final_k<<<Bn, 256, 0, stream>>>(mpart, out);
}

// Round 12
// 391.842 us; speedup vs baseline: 1.0881x; 1.0620x over previous
//
#include <hip/hip_runtime.h>
#include <hip/hip_bf16.h>
#include <math.h>

// Problem constants
#define Bn 4
#define Ln 1024
#define Vn 64
#define Dn 256
#define Hn 4
#define DKn 64
#define NLn 4
#define Mn 20
#define FFn 1024
#define NTOK (Bn * Ln)   // 4096
#define QKVW 768         // fused q|k|v width
#define LOG2E 1.4426950408889634f
#define PELEMS (Bn * Hn * Ln * Ln)   // 16777216 elements per layer P

typedef __attribute__((ext_vector_type(8))) short bf16x8;
typedef __attribute__((ext_vector_type(4))) float f32x4;

__device__ __forceinline__ ushort f2b(float f) {   // fp32 -> bf16 RNE
    uint u = __float_as_uint(f);
    u += 0x7fff + ((u >> 16) & 1);
    return (ushort)(u >> 16);
}
__device__ __forceinline__ float b2f(ushort u) {   // exact
    return __uint_as_float(((uint)u) << 16);
}

// ---------------------------------------------------------------------------
__global__ __launch_bounds__(256) void embed_k(const float* __restrict__ X,
                                               const float* __restrict__ E,
                                               ushort* __restrict__ Hb) {
    __shared__ float xs[Vn];
    int n = blockIdx.x, d = threadIdx.x;
    if (threadIdx.x < Vn) xs[threadIdx.x] = X[n * Vn + threadIdx.x];
    __syncthreads();
    float s = 0.f;
#pragma unroll
    for (int v = 0; v < Vn; ++v) s += xs[v] * E[v * Dn + d];
    Hb[(size_t)n * Dn + d] = f2b(s);
}

// ---------------------------------------------------------------------------
// bias tables, pre-scaled into exp2 domain
__global__ __launch_bounds__(256) void relbias_k(const float* __restrict__ rk,
                                                 const float* __restrict__ rb,
                                                 float* __restrict__ bkT,
                                                 float* __restrict__ bbT) {
    int tid = blockIdx.x * 256 + threadIdx.x;   // < NL*H*1024
    int dist = tid & 1023;
    int hh = (tid >> 10) & 3;
    int l = tid >> 12;
    float dd = (float)dist;
    if (dist > Mn) dd = (float)Mn + log2f((float)(dist - Mn));
    if (dd > 2.0f * Mn) dd = 2.0f * Mn;
    int idx = (int)dd;
    bkT[tid] = rk[(l * (2 * Mn + 1) + idx) * Hn + hh] * 0.125f * LOG2E;
    bbT[tid] = rb[(l * (2 * Mn + 1) + idx) * Hn + hh] * LOG2E;
}

// ---------------------------------------------------------------------------
__global__ __launch_bounds__(256) void prep_bias(const float* __restrict__ bq,
                                                 const float* __restrict__ bk,
                                                 const float* __restrict__ bv,
                                                 float* __restrict__ bqkv) {
    int idx = blockIdx.x * 256 + threadIdx.x;   // < NL*768
    int l = idx / QKVW, r = idx - l * QKVW;
    float v;
    if (r < 256)      v = bq[l * 256 + r];
    else if (r < 512) v = bk[l * 256 + r - 256];
    else              v = bv[l * 256 + r - 512];
    bqkv[idx] = v;
}

// ---------------------------------------------------------------------------
// Weight transpose + fp32->bf16: dst[c][r] = src[r][c]; grid.z = layer.
__global__ __launch_bounds__(256) void transpose_cvt(
    const float* __restrict__ src, ushort* __restrict__ dst,
    int R, int C, int srcLS, int dstLS) {
    __shared__ float s[32][33];
    src += (size_t)blockIdx.z * srcLS;
    dst += (size_t)blockIdx.z * dstLS;
    int r0 = blockIdx.y * 32, c0 = blockIdx.x * 32;
    int tx = threadIdx.x & 31, ty = threadIdx.x >> 5;
#pragma unroll
    for (int ii = 0; ii < 4; ++ii)
        s[ty + 8 * ii][tx] = src[(size_t)(r0 + ty + 8 * ii) * C + c0 + tx];
    __syncthreads();
#pragma unroll
    for (int ii = 0; ii < 4; ++ii)
        dst[(size_t)(c0 + ty + 8 * ii) * R + r0 + tx] = f2b(s[tx][ty + 8 * ii]);
}

// ---------------------------------------------------------------------------
// bf16 MFMA GEMM: C[m][n] = act(sum_k LN?(A)[m][k]*Bt[n][k] + bias[n]), C bf16.
// LNA=1: LayerNorm(A row) fused into A staging (requires K==256).
// Vt_out: if non-null, blocks with nBase>=512 write transposed into Vt
// ([bh][d][token]) instead of C (used to fold V-transpose into the QKV GEMM).
#define GST 40
#define GEMM_FRAG_MFMA                                                        \
    bf16x8 a0 = *(const bf16x8*)&As[(wm * 32 + l15) * GST + lg * 8];          \
    bf16x8 a1 = *(const bf16x8*)&As[(wm * 32 + 16 + l15) * GST + lg * 8];     \
    bf16x8 b0 = *(const bf16x8*)&Bs[(wn * 32 + l15) * GST + lg * 8];          \
    bf16x8 b1 = *(const bf16x8*)&Bs[(wn * 32 + 16 + l15) * GST + lg * 8];     \
    acc[0][0] = __builtin_amdgcn_mfma_f32_16x16x32_bf16(a0, b0, acc[0][0], 0, 0, 0); \
    acc[0][1] = __builtin_amdgcn_mfma_f32_16x16x32_bf16(a0, b1, acc[0][1], 0, 0, 0); \
    acc[1][0] = __builtin_amdgcn_mfma_f32_16x16x32_bf16(a1, b0, acc[1][0], 0, 0, 0); \
    acc[1][1] = __builtin_amdgcn_mfma_f32_16x16x32_bf16(a1, b1, acc[1][1], 0, 0, 0);

template <int LNA>
__global__ __launch_bounds__(256) void gemm_mfma(
    const ushort* __restrict__ A, const ushort* __restrict__ Bt,
    const float* __restrict__ bias, ushort* __restrict__ C,
    int M, int N, int K, int act,
    const float* __restrict__ lng, const float* __restrict__ lnb,
    ushort* __restrict__ Vt_out) {
    __shared__ __align__(16) ushort As[64 * GST];
    __shared__ __align__(16) ushort Bs[64 * GST];
    __shared__ float gl[256];
    __shared__ float bl[256];
    int t = threadIdx.x;
    int lane = t & 63, w = t >> 6;
    int wm = w >> 1, wn = w & 1;
    int l15 = lane & 15, lg = lane >> 4;
    int mBase = blockIdx.y * 64, nBase = blockIdx.x * 64;
    int lrow = t >> 2, lkc = (t & 3) * 8;
    const ushort* Ap = A + (size_t)(mBase + lrow) * K + lkc;
    const ushort* Bp = Bt + (size_t)(nBase + lrow) * K + lkc;
    f32x4 acc[2][2] = {};

    if constexpr (LNA) {
        uint4 areg[8];
        float s = 0.f;
#pragma unroll
        for (int kc = 0; kc < 8; ++kc) {
            areg[kc] = *(const uint4*)(Ap + kc * 32);
            const ushort* e = (const ushort*)&areg[kc];
#pragma unroll
            for (int q = 0; q < 8; ++q) s += b2f(e[q]);
        }
        s += __shfl_xor(s, 1, 64);
        s += __shfl_xor(s, 2, 64);
        float mu = s * (1.0f / 256.0f);
        float vv = 0.f;
#pragma unroll
        for (int kc = 0; kc < 8; ++kc) {
            const ushort* e = (const ushort*)&areg[kc];
#pragma unroll
            for (int q = 0; q < 8; ++q) {
                float d = b2f(e[q]) - mu;
                vv += d * d;
            }
        }
        vv += __shfl_xor(vv, 1, 64);
        vv += __shfl_xor(vv, 2, 64);
        float rs = rsqrtf(vv * (1.0f / 256.0f) + 1e-5f);
        gl[t] = lng[t];
        bl[t] = lnb[t];
        __syncthreads();
#pragma unroll
        for (int kc = 0; kc < 8; ++kc) {
            uint4 bv = *(const uint4*)(Bp + kc * 32);
            __syncthreads();
            {
                const ushort* e = (const ushort*)&areg[kc];
                ushort outv[8];
#pragma unroll
                for (int q = 0; q < 8; ++q) {
                    int col = kc * 32 + lkc + q;
                    outv[q] = f2b((b2f(e[q]) - mu) * rs * gl[col] + bl[col]);
                }
                *(uint4*)&As[lrow * GST + lkc] = *(const uint4*)outv;
            }
            *(uint4*)&Bs[lrow * GST + lkc] = bv;
            __syncthreads();
            GEMM_FRAG_MFMA
        }
    } else {
        for (int k0 = 0; k0 < K; k0 += 32) {
            uint4 av = *(const uint4*)(Ap + k0);
            uint4 bv = *(const uint4*)(Bp + k0);
            __syncthreads();
            *(uint4*)&As[lrow * GST + lkc] = av;
            *(uint4*)&Bs[lrow * GST + lkc] = bv;
            __syncthreads();
            GEMM_FRAG_MFMA
        }
    }
    if (Vt_out != nullptr && nBase >= 512) {
        // V section: write transposed to Vt[((b*4+hh)*64+dd)][token]
#pragma unroll
        for (int ni = 0; ni < 2; ++ni) {
            int col = nBase + wn * 32 + ni * 16 + l15;
            float bc = bias[col];
            int d = col - 512;
#pragma unroll
            for (int mi = 0; mi < 2; ++mi) {
                int rb = mBase + wm * 32 + mi * 16 + lg * 4;
                int bb_ = rb >> 10, i_ = rb & 1023;
                size_t vb = ((size_t)(bb_ * 4 + (d >> 6)) * 64 + (d & 63)) * Ln + i_;
                ushort o4[4];
#pragma unroll
                for (int j = 0; j < 4; ++j) o4[j] = f2b(acc[mi][ni][j] + bc);
                *(ushort4*)&Vt_out[vb] = *(const ushort4*)o4;
            }
        }
        return;
    }
#pragma unroll
    for (int ni = 0; ni < 2; ++ni) {
        int col = nBase + wn * 32 + ni * 16 + l15;
        float bc = bias[col];
#pragma unroll
        for (int mi = 0; mi < 2; ++mi) {
            int rb = mBase + wm * 32 + mi * 16 + lg * 4;
#pragma unroll
            for (int j = 0; j < 4; ++j) {
                float v = acc[mi][ni][j] + bc;
                if (act) v = v * 0.5f * (1.0f + erff(v * 0.7071067811865475f));
                C[(size_t)(rb + j) * N + col] = f2b(v);
            }
        }
    }
}

// ---------------------------------------------------------------------------
// MFMA flash attention, 8 waves, ~29.7KB LDS -> 4 blocks/CU (32 waves).
// Pw (PV staging) and Opart (final reduce) alias the same LDS region,
// separated by a barrier. MODE 0: f32 RMW into avg (fallback).
// MODE 1: stream P bf16 to Pout. MODE 2 (last layer): read P0..P2 from Pout
// and write final avg f32 directly (no separate avg pass).
#define PWST 40   // ushort stride per P row (80B, 16B-aligned)
#define NW 8
template <int MODE>
__global__ __launch_bounds__(512) void attn_fused(
    const ushort* __restrict__ qkv, const ushort* __restrict__ Vt,
    const float* __restrict__ bkTab, const float* __restrict__ bbTab,
    ushort* __restrict__ ctx, float* __restrict__ avg,
    ushort* __restrict__ Pout, int first) {
    __shared__ float bk_l[Ln];
    __shared__ float bb_l[Ln];
    __shared__ __align__(16) char uni[20480];   // Pw: 8x2560 | Opart: 4x4096
    __shared__ float mm[NW][16];
    __shared__ float ll[NW][16];

    int t = threadIdx.x;
    int lane = t & 63, w = t >> 6;        // w in [0,8)
    int wn = w & 3, wc = w >> 2;          // col slice, chunk half
    int l15 = lane & 15, lg = lane >> 4;

    ushort* pwh = (ushort*)&uni[w * 2560];          // [16*PWST] P hi
    ushort* pwl = (ushort*)&uni[w * 2560 + 1280];   // [16*PWST] P lo

    int bid = blockIdx.x;
    int xcd = bid & 7, sub = bid >> 3;    // sub in [0,128)
    int bh = xcd * 2 + (sub >> 6);
    int q = sub & 63;
    int b = bh >> 2, hh = bh & 3;
    int i0 = q * 16;

#pragma unroll
    for (int ii = 0; ii < 2; ++ii) {
        bk_l[t + 512 * ii] = bkTab[hh * Ln + t + 512 * ii];
        bb_l[t + 512 * ii] = bbTab[hh * Ln + t + 512 * ii];
    }
    __syncthreads();

    // Q fragment (A-operand): row = i0 + l15, k = lg*8 (+32)
    bf16x8 qa0, qa1;
    {
        const ushort* qp = qkv + (size_t)(b * Ln + i0 + l15) * QKVW + hh * DKn;
        qa0 = *(const bf16x8*)(qp + lg * 8);
        qa1 = *(const bf16x8*)(qp + 32 + lg * 8);
    }

    const ushort* kbase = qkv + (size_t)(b * Ln) * QKVW + Dn + hh * DKn;

    // ---- QK pass over this wave's 8 chunks (barrier-free) -------------------
    f32x4 sv[8];
    float m[4] = {-1e30f, -1e30f, -1e30f, -1e30f};
#pragma unroll
    for (int cl = 0; cl < 8; ++cl) {
        int c = wc * 8 + cl;
        const ushort* kp = kbase + (size_t)(c * 64 + wn * 16 + l15) * QKVW;
        bf16x8 k0 = *(const bf16x8*)(kp + lg * 8);
        bf16x8 k1 = *(const bf16x8*)(kp + 32 + lg * 8);
        f32x4 acc = {};
        acc = __builtin_amdgcn_mfma_f32_16x16x32_bf16(qa0, k0, acc, 0, 0, 0);
        acc = __builtin_amdgcn_mfma_f32_16x16x32_bf16(qa1, k1, acc, 0, 0, 0);
        int j = c * 64 + wn * 16 + l15;
#pragma unroll
        for (int r = 0; r < 4; ++r) {
            int i = i0 + lg * 4 + r;
            int dist = (i > j) ? (i - j) : (j - i);
            float s = acc[r] * bk_l[dist] + bb_l[dist];
            sv[cl][r] = s;
            m[r] = fmaxf(m[r], s);
        }
    }
    // merge max over the 16 l15-lanes
#pragma unroll
    for (int mask = 1; mask < 16; mask <<= 1)
#pragma unroll
        for (int r = 0; r < 4; ++r) m[r] = fmaxf(m[r], __shfl_xor(m[r], mask, 64));
    // merge max across the 8 waves
    if (l15 == 0)
#pragma unroll
        for (int r = 0; r < 4; ++r) mm[w][lg * 4 + r] = m[r];
    __syncthreads();
#pragma unroll
    for (int r = 0; r < 4; ++r) {
        int row = lg * 4 + r;
        float m0 = fmaxf(fmaxf(mm[0][row], mm[1][row]), fmaxf(mm[2][row], mm[3][row]));
        float m1 = fmaxf(fmaxf(mm[4][row], mm[5][row]), fmaxf(mm[6][row], mm[7][row]));
        m[r] = fmaxf(m0, m1);
    }
    // p_unnorm = exp2(s - m); row sums
    float lsum[4] = {0.f, 0.f, 0.f, 0.f};
#pragma unroll
    for (int cl = 0; cl < 8; ++cl)
#pragma unroll
        for (int r = 0; r < 4; ++r) {
            float p = exp2f(sv[cl][r] - m[r]);
            sv[cl][r] = p;
            lsum[r] += p;
        }
#pragma unroll
    for (int mask = 1; mask < 16; mask <<= 1)
#pragma unroll
        for (int r = 0; r < 4; ++r) lsum[r] += __shfl_xor(lsum[r], mask, 64);
    if (l15 == 0)
#pragma unroll
        for (int r = 0; r < 4; ++r) ll[w][lg * 4 + r] = lsum[r];
    __syncthreads();
    float invl[4];
#pragma unroll
    for (int r = 0; r < 4; ++r) {
        int row = lg * 4 + r;
        invl[r] = 1.0f / (ll[0][row] + ll[1][row] + ll[2][row] + ll[3][row] +
                          ll[4][row] + ll[5][row] + ll[6][row] + ll[7][row]);
    }

    // ---- PV partial-O + P/avg output: ZERO barriers --------------------------
    const ushort* vbase = Vt + (size_t)bh * DKn * Ln;       // [64 d][Ln k]
    float* avgrow = avg + ((size_t)bh * Ln + i0) * Ln;      // MODE 0
    ushort* prow = Pout + ((size_t)bh * Ln + i0) * Ln;      // MODE 1
    int iw = lane >> 2, jq = lane & 3;                      // P-store map
    f32x4 acco[4] = {};
#pragma unroll
    for (int p = 0; p < 4; ++p) {
        const int c0 = wc * 8 + 2 * p, c1 = c0 + 1;
        float aold[2][4];
        if (MODE == 0 && !first) {
#pragma unroll
            for (int cc = 0; cc < 2; ++cc)
#pragma unroll
                for (int r = 0; r < 4; ++r)
                    aold[cc][r] = avgrow[(size_t)(lg * 4 + r) * Ln +
                                         (c0 + cc) * 64 + wn * 16 + l15];
        }
        // stage P (hi/lo) into wave-private LDS
#pragma unroll
        for (int cc = 0; cc < 2; ++cc)
#pragma unroll
            for (int r = 0; r < 4; ++r) {
                float pv = sv[2 * p + cc][r] * invl[r];
                sv[2 * p + cc][r] = pv;
                ushort ph = f2b(pv);
                int off = (lg * 4 + r) * PWST + cc * 16 + l15;
                pwh[off] = ph;
                pwl[off] = f2b(pv - b2f(ph));
            }
        // V A-fragments
        int kcol = (lg < 2 ? c0 : c1) * 64 + wn * 16 + (lg & 1) * 8;
        bf16x8 va0 = *(const bf16x8*)(vbase + (size_t)(0 * 16 + l15) * Ln + kcol);
        bf16x8 va1 = *(const bf16x8*)(vbase + (size_t)(1 * 16 + l15) * Ln + kcol);
        bf16x8 va2 = *(const bf16x8*)(vbase + (size_t)(2 * 16 + l15) * Ln + kcol);
        bf16x8 va3 = *(const bf16x8*)(vbase + (size_t)(3 * 16 + l15) * Ln + kcol);
        // B fragments from own LDS (same-wave RAW: compiler lgkmcnt)
        bf16x8 pbh = *(const bf16x8*)&pwh[l15 * PWST + lg * 8];
        bf16x8 pbl = *(const bf16x8*)&pwl[l15 * PWST + lg * 8];
        acco[0] = __builtin_amdgcn_mfma_f32_16x16x32_bf16(va0, pbh, acco[0], 0, 0, 0);
        acco[1] = __builtin_amdgcn_mfma_f32_16x16x32_bf16(va1, pbh, acco[1], 0, 0, 0);
        acco[2] = __builtin_amdgcn_mfma_f32_16x16x32_bf16(va2, pbh, acco[2], 0, 0, 0);
        acco[3] = __builtin_amdgcn_mfma_f32_16x16x32_bf16(va3, pbh, acco[3], 0, 0, 0);
        acco[0] = __builtin_amdgcn_mfma_f32_16x16x32_bf16(va0, pbl, acco[0], 0, 0, 0);
        acco[1] = __builtin_amdgcn_mfma_f32_16x16x32_bf16(va1, pbl, acco[1], 0, 0, 0);
        acco[2] = __builtin_amdgcn_mfma_f32_16x16x32_bf16(va2, pbl, acco[2], 0, 0, 0);
        acco[3] = __builtin_amdgcn_mfma_f32_16x16x32_bf16(va3, pbl, acco[3], 0, 0, 0);
        if (MODE == 0) {
#pragma unroll
            for (int cc = 0; cc < 2; ++cc)
#pragma unroll
                for (int r = 0; r < 4; ++r) {
                    float v = 0.25f * sv[2 * p + cc][r];
                    if (!first) v += aold[cc][r];
                    avgrow[(size_t)(lg * 4 + r) * Ln + (c0 + cc) * 64 + wn * 16 + l15] = v;
                }
        } else if (MODE == 1) {
            ushort4 ph0 = *(const ushort4*)&pwh[iw * PWST + 0 * 16 + jq * 4];
            ushort4 ph1 = *(const ushort4*)&pwh[iw * PWST + 1 * 16 + jq * 4];
            *(ushort4*)&prow[(size_t)iw * Ln + c0 * 64 + wn * 16 + jq * 4] = ph0;
            *(ushort4*)&prow[(size_t)iw * Ln + c1 * 64 + wn * 16 + jq * 4] = ph1;
        } else {
            // MODE 2: final layer -> read P0..P2, add own P, write avg f32
#pragma unroll
            for (int cc = 0; cc < 2; ++cc) {
                int c = c0 + cc;
                size_t base = ((size_t)(bh * Ln) + i0 + iw) * Ln +
                              c * 64 + wn * 16 + jq * 4;
                ushort4 p0 = *(const ushort4*)&Pout[base];
                ushort4 p1 = *(const ushort4*)&Pout[(size_t)PELEMS + base];
                ushort4 p2 = *(const ushort4*)&Pout[(size_t)2 * PELEMS + base];
                ushort4 p3 = *(const ushort4*)&pwh[iw * PWST + cc * 16 + jq * 4];
                const ushort* q0 = (const ushort*)&p0;
                const ushort* q1 = (const ushort*)&p1;
                const ushort* q2 = (const ushort*)&p2;
                const ushort* q3 = (const ushort*)&p3;
                float4 o;
                float* op_ = (float*)&o;
#pragma unroll
                for (int k = 0; k < 4; ++k)
                    op_[k] = 0.25f * (b2f(q0[k]) + b2f(q1[k]) + b2f(q2[k]) + b2f(q3[k]));
                *(float4*)&avg[base] = o;
            }
        }
    }

    // ---- reduce partial O across 8 waves (Opart aliases Pw) ------------------
    __syncthreads();   // all PV done; Pw region dead
    {
        float* op = (float*)&uni[wn * 4096];
        if (wc == 1) {
#pragma unroll
            for (int dg = 0; dg < 4; ++dg)
#pragma unroll
                for (int r = 0; r < 4; ++r)
                    op[(dg * 16 + lg * 4 + r) * 16 + l15] = acco[dg][r];
        }
    }
    __syncthreads();
    {
        float* op = (float*)&uni[wn * 4096];
        if (wc == 0) {
#pragma unroll
            for (int dg = 0; dg < 4; ++dg)
#pragma unroll
                for (int r = 0; r < 4; ++r)
                    op[(dg * 16 + lg * 4 + r) * 16 + l15] += acco[dg][r];
        }
    }
    __syncthreads();
#pragma unroll
    for (int k = 0; k < 2; ++k) {
        int idx = t + 512 * k;          // idx = d*16 + i
        float v = ((const float*)&uni[0])[idx] + ((const float*)&uni[4096])[idx] +
                  ((const float*)&uni[8192])[idx] + ((const float*)&uni[12288])[idx];
        int dd = idx >> 4, ii = idx & 15;
        ctx[(size_t)(b * Ln + i0 + ii) * Dn + hh * DKn + dd] = f2b(v);
    }
}

// ---------------------------------------------------------------------------
__global__ __launch_bounds__(256) void layernorm_k(const ushort* __restrict__ X,
                                                   const float* __restrict__ g,
                                                   const float* __restrict__ bta,
                                                   ushort* __restrict__ Y) {
    int w = threadIdx.x >> 6, lane = threadIdx.x & 63;
    int row = blockIdx.x * 4 + w;
    const ushort* xr = X + (size_t)row * Dn;
    float x[4];
#pragma unroll
    for (int ii = 0; ii < 4; ++ii) x[ii] = b2f(xr[lane + 64 * ii]);
    float s = x[0] + x[1] + x[2] + x[3];
#pragma unroll
    for (int m = 1; m < 64; m <<= 1) s += __shfl_xor(s, m, 64);
    float mu = s * (1.0f / 256.0f);
    float vs = 0.f;
#pragma unroll
    for (int ii = 0; ii < 4; ++ii) {
        float d = x[ii] - mu;
        vs += d * d;
    }
#pragma unroll
    for (int m = 1; m < 64; m <<= 1) vs += __shfl_xor(vs, m, 64);
    float rs = rsqrtf(vs * (1.0f / 256.0f) + 1e-5f);
#pragma unroll
    for (int ii = 0; ii < 4; ++ii) {
        int d = lane + 64 * ii;
        Y[(size_t)row * Dn + d] = f2b((x[ii] - mu) * rs * g[d] + bta[d]);
    }
}

// ---------------------------------------------------------------------------
__global__ __launch_bounds__(256) void mean_part_k(const ushort* __restrict__ Hb,
                                                   float* __restrict__ part) {
    int blk = blockIdx.x;            // 64 = 4 b x 16 groups
    int b = blk >> 4, g = blk & 15;
    int d = threadIdx.x;
    float s = 0.f;
#pragma unroll
    for (int r = 0; r < 64; ++r)
        s += b2f(Hb[(size_t)(b * Ln + g * 64 + r) * Dn + d]);
    part[(size_t)blk * Dn + d] = s;
}
__global__ __launch_bounds__(256) void mean_final_k(const float* __restrict__ part,
                                                    float* __restrict__ out) {
    int b = blockIdx.x, d = threadIdx.x;
    float s = 0.f;
#pragma unroll
    for (int g = 0; g < 16; ++g) s += part[(size_t)(b * 16 + g) * Dn + d];
    out[b * Dn + d] = s * (1.0f / (float)Ln);
}

// ---------------------------------------------------------------------------
extern "C" void kernel_launch(void* const* d_in, const int* in_sizes, int n_in,
                              void* d_out, int out_size, void* d_ws, size_t ws_size,
                              hipStream_t stream) {
    const float* x    = (const float*)d_in[0];
    const float* emb  = (const float*)d_in[1];
    const float* Wq   = (const float*)d_in[2];
    const float* bq   = (const float*)d_in[3];
    const float* Wk   = (const float*)d_in[4];
    const float* bk   = (const float*)d_in[5];
    const float* Wv   = (const float*)d_in[6];
    const float* bv   = (const float*)d_in[7];
    const float* Wo   = (const float*)d_in[8];
    const float* bo   = (const float*)d_in[9];
    const float* rk   = (const float*)d_in[10];
    const float* rb   = (const float*)d_in[11];
    const float* ln1g = (const float*)d_in[12];
    const float* ln1b = (const float*)d_in[13];
    const float* W1   = (const float*)d_in[14];
    const float* b1   = (const float*)d_in[15];
    const float* W2   = (const float*)d_in[16];
    const float* b2   = (const float*)d_in[17];
    const float* ln2g = (const float*)d_in[18];
    const float* ln2b = (const float*)d_in[19];

    float* out = (float*)d_out;
    float* avg = out + Bn * Dn;

    char* ws = (char*)d_ws;
    const size_t MB = 1024 * 1024;
    ushort* hb   = (ushort*)(ws);             // 2 MB
    ushort* qkvb = (ushort*)(ws + 2 * MB);    // 6 MB
    ushort* ctxb = (ushort*)(ws + 8 * MB);    // 2 MB
    ushort* t1   = (ushort*)(ws + 10 * MB);   // 2 MB
    ushort* ffb  = (ushort*)(ws + 12 * MB);   // 8 MB
    ushort* qkvT = (ushort*)(ws + 20 * MB);   // 1.5 MB
    ushort* WoT  = (ushort*)(ws + 22 * MB);   // 0.5 MB
    ushort* W1T  = (ushort*)(ws + 23 * MB);   // 2 MB
    ushort* W2T  = (ushort*)(ws + 25 * MB);   // 2 MB
    float*  bqkv = (float*)(ws + 27 * MB);
    float*  bkT  = (float*)(ws + 27 * MB + 65536);
    float*  bbT  = (float*)(ws + 27 * MB + 131072);
    ushort* Vt   = (ushort*)(ws + 30 * MB);   // 2 MB
    float*  mpart= (float*)(ws + 33 * MB);    // 64 KB
    ushort* Pbuf = (ushort*)(ws + 36 * MB);   // 3 x 32 MB used (mode 1/2)

    const size_t need = 36 * MB + (size_t)3 * PELEMS * sizeof(ushort);
    const bool fancy = (ws_size >= need);

    embed_k<<<NTOK, 256, 0, stream>>>(x, emb, hb);
    relbias_k<<<64, 256, 0, stream>>>(rk, rb, bkT, bbT);
    prep_bias<<<12, 256, 0, stream>>>(bq, bk, bv, bqkv);

    dim3 t88(8, 8, NLn);
    transpose_cvt<<<t88, 256, 0, stream>>>(Wq, qkvT + 0,      256, 256, 65536, 196608);
    transpose_cvt<<<t88, 256, 0, stream>>>(Wk, qkvT + 65536,  256, 256, 65536, 196608);
    transpose_cvt<<<t88, 256, 0, stream>>>(Wv, qkvT + 131072, 256, 256, 65536, 196608);
    transpose_cvt<<<t88, 256, 0, stream>>>(Wo, WoT,           256, 256, 65536, 65536);
    transpose_cvt<<<dim3(32, 8, NLn), 256, 0, stream>>>(W1, W1T, 256, 1024, 262144, 262144);
    transpose_cvt<<<dim3(8, 32, NLn), 256, 0, stream>>>(W2, W2T, 1024, 256, 262144, 262144);

    for (int l = 0; l < NLn; ++l) {
        // QKV projection (V written transposed into Vt via epilogue);
        // layers 1..3 fuse previous layer's ln2 into A.
        if (l == 0) {
            gemm_mfma<0><<<dim3(12, 64), 256, 0, stream>>>(
                hb, qkvT + (size_t)l * 196608, bqkv + l * QKVW, qkvb,
                NTOK, QKVW, Dn, 0, nullptr, nullptr, Vt);
        } else {
            gemm_mfma<1><<<dim3(12, 64), 256, 0, stream>>>(
                hb, qkvT + (size_t)l * 196608, bqkv + l * QKVW, qkvb,
                NTOK, QKVW, Dn, 0, ln2g + (l - 1) * 256, ln2b + (l - 1) * 256, Vt);
        }
        if (fancy) {
            if (l < 3) {
                attn_fused<1><<<1024, 512, 0, stream>>>(
                    qkvb, Vt, bkT + l * Hn * Ln, bbT + l * Hn * Ln, ctxb, avg,
                    Pbuf + (size_t)l * PELEMS, 0);
            } else {
                attn_fused<2><<<1024, 512, 0, stream>>>(
                    qkvb, Vt, bkT + l * Hn * Ln, bbT + l * Hn * Ln, ctxb, avg,
                    Pbuf, 0);
            }
        } else {
            attn_fused<0><<<1024, 512, 0, stream>>>(
                qkvb, Vt, bkT + l * Hn * Ln, bbT + l * Hn * Ln, ctxb, avg,
                (ushort*)Pbuf, (l == 0) ? 1 : 0);
        }
        gemm_mfma<0><<<dim3(4, 64), 256, 0, stream>>>(
            ctxb, WoT + (size_t)l * 65536, bo + l * 256, t1,
            NTOK, Dn, Dn, 0, nullptr, nullptr, nullptr);
        // FF1 with fused ln1 + exact GELU
        gemm_mfma<1><<<dim3(16, 64), 256, 0, stream>>>(
            t1, W1T + (size_t)l * 262144, b1 + l * FFn, ffb,
            NTOK, FFn, Dn, 1, ln1g + l * 256, ln1b + l * 256, nullptr);
        gemm_mfma<0><<<dim3(4, 64), 256, 0, stream>>>(
            ffb, W2T + (size_t)l * 262144, b2 + l * 256, hb,
            NTOK, Dn, FFn, 0, nullptr, nullptr, nullptr);
    }
    // final ln2 (layer 3) before the mean
    layernorm_k<<<NTOK / 4, 256, 0, stream>>>(
        hb, ln2g + 3 * 256, ln2b + 3 * 256, hb);
    mean_part_k<<<64, 256, 0, stream>>>(hb, mpart);
    mean_final_k<<<Bn, 256, 0, stream>>>(mpart, out);
}

// Round 13
// 376.519 us; speedup vs baseline: 1.1324x; 1.0407x over previous
//
#include <hip/hip_runtime.h>
#include <hip/hip_bf16.h>
#include <math.h>

// Problem constants
#define Bn 4
#define Ln 1024
#define Vn 64
#define Dn 256
#define Hn 4
#define DKn 64
#define NLn 4
#define Mn 20
#define FFn 1024
#define NTOK (Bn * Ln)   // 4096
#define QKVW 768         // fused q|k|v width
#define LOG2E 1.4426950408889634f
#define PELEMS (Bn * Hn * Ln * Ln)   // 16777216 elements per layer P

typedef __attribute__((ext_vector_type(8))) short bf16x8;
typedef __attribute__((ext_vector_type(4))) float f32x4;

__device__ __forceinline__ ushort f2b(float f) {   // fp32 -> bf16 RNE
    uint u = __float_as_uint(f);
    u += 0x7fff + ((u >> 16) & 1);
    return (ushort)(u >> 16);
}
__device__ __forceinline__ float b2f(ushort u) {   // exact
    return __uint_as_float(((uint)u) << 16);
}

// ---------------------------------------------------------------------------
__global__ __launch_bounds__(256) void embed_k(const float* __restrict__ X,
                                               const float* __restrict__ E,
                                               ushort* __restrict__ Hb) {
    __shared__ float xs[Vn];
    int n = blockIdx.x, d = threadIdx.x;
    if (threadIdx.x < Vn) xs[threadIdx.x] = X[n * Vn + threadIdx.x];
    __syncthreads();
    float s = 0.f;
#pragma unroll
    for (int v = 0; v < Vn; ++v) s += xs[v] * E[v * Dn + d];
    Hb[(size_t)n * Dn + d] = f2b(s);
}

// ---------------------------------------------------------------------------
// bias tables, pre-scaled into exp2 domain
__global__ __launch_bounds__(256) void relbias_k(const float* __restrict__ rk,
                                                 const float* __restrict__ rb,
                                                 float* __restrict__ bkT,
                                                 float* __restrict__ bbT) {
    int tid = blockIdx.x * 256 + threadIdx.x;   // < NL*H*1024
    int dist = tid & 1023;
    int hh = (tid >> 10) & 3;
    int l = tid >> 12;
    float dd = (float)dist;
    if (dist > Mn) dd = (float)Mn + log2f((float)(dist - Mn));
    if (dd > 2.0f * Mn) dd = 2.0f * Mn;
    int idx = (int)dd;
    bkT[tid] = rk[(l * (2 * Mn + 1) + idx) * Hn + hh] * 0.125f * LOG2E;
    bbT[tid] = rb[(l * (2 * Mn + 1) + idx) * Hn + hh] * LOG2E;
}

// ---------------------------------------------------------------------------
__global__ __launch_bounds__(256) void prep_bias(const float* __restrict__ bq,
                                                 const float* __restrict__ bk,
                                                 const float* __restrict__ bv,
                                                 float* __restrict__ bqkv) {
    int idx = blockIdx.x * 256 + threadIdx.x;   // < NL*768
    int l = idx / QKVW, r = idx - l * QKVW;
    float v;
    if (r < 256)      v = bq[l * 256 + r];
    else if (r < 512) v = bk[l * 256 + r - 256];
    else              v = bv[l * 256 + r - 512];
    bqkv[idx] = v;
}

// ---------------------------------------------------------------------------
// Weight transpose + fp32->bf16: dst[c][r] = src[r][c]; grid.z = layer.
__global__ __launch_bounds__(256) void transpose_cvt(
    const float* __restrict__ src, ushort* __restrict__ dst,
    int R, int C, int srcLS, int dstLS) {
    __shared__ float s[32][33];
    src += (size_t)blockIdx.z * srcLS;
    dst += (size_t)blockIdx.z * dstLS;
    int r0 = blockIdx.y * 32, c0 = blockIdx.x * 32;
    int tx = threadIdx.x & 31, ty = threadIdx.x >> 5;
#pragma unroll
    for (int ii = 0; ii < 4; ++ii)
        s[ty + 8 * ii][tx] = src[(size_t)(r0 + ty + 8 * ii) * C + c0 + tx];
    __syncthreads();
#pragma unroll
    for (int ii = 0; ii < 4; ++ii)
        dst[(size_t)(c0 + ty + 8 * ii) * R + r0 + tx] = f2b(s[tx][ty + 8 * ii]);
}

// ---------------------------------------------------------------------------
// bf16 MFMA GEMM, BK=64 (half the barriers of BK=32).
// C[m][n] = act(sum_k LN?(A)[m][k]*Bt[n][k] + bias[n]), C bf16.
// LNA=1: LayerNorm(A row) fused into A staging (requires K==256).
// Vt_out: if non-null, blocks with nBase>=512 write transposed into Vt.
#define GST 72   // ushort stride per LDS row (144B)
#define GEMM_KK_MFMA(KK)                                                      \
    {                                                                         \
        bf16x8 a0 = *(const bf16x8*)&As[(wm * 32 + l15) * GST + (KK)*32 + lg * 8];      \
        bf16x8 a1 = *(const bf16x8*)&As[(wm * 32 + 16 + l15) * GST + (KK)*32 + lg * 8]; \
        bf16x8 b0 = *(const bf16x8*)&Bs[(wn * 32 + l15) * GST + (KK)*32 + lg * 8];      \
        bf16x8 b1 = *(const bf16x8*)&Bs[(wn * 32 + 16 + l15) * GST + (KK)*32 + lg * 8]; \
        acc[0][0] = __builtin_amdgcn_mfma_f32_16x16x32_bf16(a0, b0, acc[0][0], 0, 0, 0); \
        acc[0][1] = __builtin_amdgcn_mfma_f32_16x16x32_bf16(a0, b1, acc[0][1], 0, 0, 0); \
        acc[1][0] = __builtin_amdgcn_mfma_f32_16x16x32_bf16(a1, b0, acc[1][0], 0, 0, 0); \
        acc[1][1] = __builtin_amdgcn_mfma_f32_16x16x32_bf16(a1, b1, acc[1][1], 0, 0, 0); \
    }

template <int LNA>
__global__ __launch_bounds__(256) void gemm_mfma(
    const ushort* __restrict__ A, const ushort* __restrict__ Bt,
    const float* __restrict__ bias, ushort* __restrict__ C,
    int M, int N, int K, int act,
    const float* __restrict__ lng, const float* __restrict__ lnb,
    ushort* __restrict__ Vt_out) {
    __shared__ __align__(16) ushort As[64 * GST];
    __shared__ __align__(16) ushort Bs[64 * GST];
    __shared__ float gl[256];
    __shared__ float bl[256];
    int t = threadIdx.x;
    int lane = t & 63, w = t >> 6;
    int wm = w >> 1, wn = w & 1;
    int l15 = lane & 15, lg = lane >> 4;
    int mBase = blockIdx.y * 64, nBase = blockIdx.x * 64;
    int lrow = t >> 2, lkc = (t & 3) * 16;   // 4 threads x 16 ushorts = 64 k
    const ushort* Ap = A + (size_t)(mBase + lrow) * K + lkc;
    const ushort* Bp = Bt + (size_t)(nBase + lrow) * K + lkc;
    f32x4 acc[2][2] = {};

    if constexpr (LNA) {
        // K == 256: preload the thread's 64 A elements (8 x uint4)
        uint4 areg[8];
        float s = 0.f;
#pragma unroll
        for (int kc = 0; kc < 4; ++kc)
#pragma unroll
            for (int h = 0; h < 2; ++h) {
                areg[kc * 2 + h] = *(const uint4*)(Ap + kc * 64 + h * 8);
                const ushort* e = (const ushort*)&areg[kc * 2 + h];
#pragma unroll
                for (int q = 0; q < 8; ++q) s += b2f(e[q]);
            }
        s += __shfl_xor(s, 1, 64);
        s += __shfl_xor(s, 2, 64);
        float mu = s * (1.0f / 256.0f);
        float vv = 0.f;
#pragma unroll
        for (int kc = 0; kc < 8; ++kc) {
            const ushort* e = (const ushort*)&areg[kc];
#pragma unroll
            for (int q = 0; q < 8; ++q) {
                float d = b2f(e[q]) - mu;
                vv += d * d;
            }
        }
        vv += __shfl_xor(vv, 1, 64);
        vv += __shfl_xor(vv, 2, 64);
        float rs = rsqrtf(vv * (1.0f / 256.0f) + 1e-5f);
        gl[t] = lng[t];
        bl[t] = lnb[t];
        __syncthreads();
#pragma unroll
        for (int kc = 0; kc < 4; ++kc) {
            uint4 bv0 = *(const uint4*)(Bp + kc * 64);
            uint4 bv1 = *(const uint4*)(Bp + kc * 64 + 8);
            __syncthreads();
#pragma unroll
            for (int h = 0; h < 2; ++h) {
                const ushort* e = (const ushort*)&areg[kc * 2 + h];
                ushort outv[8];
#pragma unroll
                for (int q = 0; q < 8; ++q) {
                    int col = kc * 64 + lkc + h * 8 + q;
                    outv[q] = f2b((b2f(e[q]) - mu) * rs * gl[col] + bl[col]);
                }
                *(uint4*)&As[lrow * GST + lkc + h * 8] = *(const uint4*)outv;
            }
            *(uint4*)&Bs[lrow * GST + lkc] = bv0;
            *(uint4*)&Bs[lrow * GST + lkc + 8] = bv1;
            __syncthreads();
            GEMM_KK_MFMA(0)
            GEMM_KK_MFMA(1)
        }
    } else {
        for (int k0 = 0; k0 < K; k0 += 64) {
            uint4 av0 = *(const uint4*)(Ap + k0);
            uint4 av1 = *(const uint4*)(Ap + k0 + 8);
            uint4 bv0 = *(const uint4*)(Bp + k0);
            uint4 bv1 = *(const uint4*)(Bp + k0 + 8);
            __syncthreads();
            *(uint4*)&As[lrow * GST + lkc] = av0;
            *(uint4*)&As[lrow * GST + lkc + 8] = av1;
            *(uint4*)&Bs[lrow * GST + lkc] = bv0;
            *(uint4*)&Bs[lrow * GST + lkc + 8] = bv1;
            __syncthreads();
            GEMM_KK_MFMA(0)
            GEMM_KK_MFMA(1)
        }
    }
    if (Vt_out != nullptr && nBase >= 512) {
        // V section: write transposed to Vt[((b*4+hh)*64+dd)][token]
#pragma unroll
        for (int ni = 0; ni < 2; ++ni) {
            int col = nBase + wn * 32 + ni * 16 + l15;
            float bc = bias[col];
            int d = col - 512;
#pragma unroll
            for (int mi = 0; mi < 2; ++mi) {
                int rb = mBase + wm * 32 + mi * 16 + lg * 4;
                int bb_ = rb >> 10, i_ = rb & 1023;
                size_t vb = ((size_t)(bb_ * 4 + (d >> 6)) * 64 + (d & 63)) * Ln + i_;
                ushort o4[4];
#pragma unroll
                for (int j = 0; j < 4; ++j) o4[j] = f2b(acc[mi][ni][j] + bc);
                *(ushort4*)&Vt_out[vb] = *(const ushort4*)o4;
            }
        }
        return;
    }
#pragma unroll
    for (int ni = 0; ni < 2; ++ni) {
        int col = nBase + wn * 32 + ni * 16 + l15;
        float bc = bias[col];
#pragma unroll
        for (int mi = 0; mi < 2; ++mi) {
            int rb = mBase + wm * 32 + mi * 16 + lg * 4;
#pragma unroll
            for (int j = 0; j < 4; ++j) {
                float v = acc[mi][ni][j] + bc;
                if (act) v = v * 0.5f * (1.0f + erff(v * 0.7071067811865475f));
                C[(size_t)(rb + j) * N + col] = f2b(v);
            }
        }
    }
}

// ---------------------------------------------------------------------------
// MFMA flash attention, 8 waves, ~29.7KB LDS -> 4 blocks/CU. Pw/Opart alias.
// MODE 0: f32 RMW into avg (fallback). MODE 1: stream P bf16 to Pout in
// TILE-LINEAR layout (512B coalesced per wave instr). MODE 2 (last layer):
// read P0..P2 tile-linear + own P, write final avg f32.
#define PWST 40   // ushort stride per P row (80B, 16B-aligned)
#define NW 8
template <int MODE>
__global__ __launch_bounds__(512) void attn_fused(
    const ushort* __restrict__ qkv, const ushort* __restrict__ Vt,
    const float* __restrict__ bkTab, const float* __restrict__ bbTab,
    ushort* __restrict__ ctx, float* __restrict__ avg,
    ushort* __restrict__ Pout, int first) {
    __shared__ float bk_l[Ln];
    __shared__ float bb_l[Ln];
    __shared__ __align__(16) char uni[20480];   // Pw: 8x2560 | Opart: 4x4096
    __shared__ float mm[NW][16];
    __shared__ float ll[NW][16];

    int t = threadIdx.x;
    int lane = t & 63, w = t >> 6;        // w in [0,8)
    int wn = w & 3, wc = w >> 2;          // col slice, chunk half
    int l15 = lane & 15, lg = lane >> 4;

    ushort* pwh = (ushort*)&uni[w * 2560];          // [16*PWST] P hi
    ushort* pwl = (ushort*)&uni[w * 2560 + 1280];   // [16*PWST] P lo

    int bid = blockIdx.x;
    int xcd = bid & 7, sub = bid >> 3;    // sub in [0,128)
    int bh = xcd * 2 + (sub >> 6);
    int q = sub & 63;
    int b = bh >> 2, hh = bh & 3;
    int i0 = q * 16;

#pragma unroll
    for (int ii = 0; ii < 2; ++ii) {
        bk_l[t + 512 * ii] = bkTab[hh * Ln + t + 512 * ii];
        bb_l[t + 512 * ii] = bbTab[hh * Ln + t + 512 * ii];
    }
    __syncthreads();

    // Q fragment (A-operand): row = i0 + l15, k = lg*8 (+32)
    bf16x8 qa0, qa1;
    {
        const ushort* qp = qkv + (size_t)(b * Ln + i0 + l15) * QKVW + hh * DKn;
        qa0 = *(const bf16x8*)(qp + lg * 8);
        qa1 = *(const bf16x8*)(qp + 32 + lg * 8);
    }

    const ushort* kbase = qkv + (size_t)(b * Ln) * QKVW + Dn + hh * DKn;

    // ---- QK pass over this wave's 8 chunks (barrier-free) -------------------
    f32x4 sv[8];
    float m[4] = {-1e30f, -1e30f, -1e30f, -1e30f};
#pragma unroll
    for (int cl = 0; cl < 8; ++cl) {
        int c = wc * 8 + cl;
        const ushort* kp = kbase + (size_t)(c * 64 + wn * 16 + l15) * QKVW;
        bf16x8 k0 = *(const bf16x8*)(kp + lg * 8);
        bf16x8 k1 = *(const bf16x8*)(kp + 32 + lg * 8);
        f32x4 acc = {};
        acc = __builtin_amdgcn_mfma_f32_16x16x32_bf16(qa0, k0, acc, 0, 0, 0);
        acc = __builtin_amdgcn_mfma_f32_16x16x32_bf16(qa1, k1, acc, 0, 0, 0);
        int j = c * 64 + wn * 16 + l15;
#pragma unroll
        for (int r = 0; r < 4; ++r) {
            int i = i0 + lg * 4 + r;
            int dist = (i > j) ? (i - j) : (j - i);
            float s = acc[r] * bk_l[dist] + bb_l[dist];
            sv[cl][r] = s;
            m[r] = fmaxf(m[r], s);
        }
    }
    // merge max over the 16 l15-lanes
#pragma unroll
    for (int mask = 1; mask < 16; mask <<= 1)
#pragma unroll
        for (int r = 0; r < 4; ++r) m[r] = fmaxf(m[r], __shfl_xor(m[r], mask, 64));
    // merge max across the 8 waves
    if (l15 == 0)
#pragma unroll
        for (int r = 0; r < 4; ++r) mm[w][lg * 4 + r] = m[r];
    __syncthreads();
#pragma unroll
    for (int r = 0; r < 4; ++r) {
        int row = lg * 4 + r;
        float m0 = fmaxf(fmaxf(mm[0][row], mm[1][row]), fmaxf(mm[2][row], mm[3][row]));
        float m1 = fmaxf(fmaxf(mm[4][row], mm[5][row]), fmaxf(mm[6][row], mm[7][row]));
        m[r] = fmaxf(m0, m1);
    }
    // p_unnorm = exp2(s - m); row sums
    float lsum[4] = {0.f, 0.f, 0.f, 0.f};
#pragma unroll
    for (int cl = 0; cl < 8; ++cl)
#pragma unroll
        for (int r = 0; r < 4; ++r) {
            float p = exp2f(sv[cl][r] - m[r]);
            sv[cl][r] = p;
            lsum[r] += p;
        }
#pragma unroll
    for (int mask = 1; mask < 16; mask <<= 1)
#pragma unroll
        for (int r = 0; r < 4; ++r) lsum[r] += __shfl_xor(lsum[r], mask, 64);
    if (l15 == 0)
#pragma unroll
        for (int r = 0; r < 4; ++r) ll[w][lg * 4 + r] = lsum[r];
    __syncthreads();
    float invl[4];
#pragma unroll
    for (int r = 0; r < 4; ++r) {
        int row = lg * 4 + r;
        invl[r] = 1.0f / (ll[0][row] + ll[1][row] + ll[2][row] + ll[3][row] +
                          ll[4][row] + ll[5][row] + ll[6][row] + ll[7][row]);
    }

    // ---- PV partial-O + P/avg output: ZERO barriers --------------------------
    const ushort* vbase = Vt + (size_t)bh * DKn * Ln;       // [64 d][Ln k]
    float* avgrow = avg + ((size_t)bh * Ln + i0) * Ln;      // MODE 0
    int iw = lane >> 2, jq = lane & 3;                      // P tile map
    f32x4 acco[4] = {};
#pragma unroll
    for (int p = 0; p < 4; ++p) {
        const int c0 = wc * 8 + 2 * p, c1 = c0 + 1;
        float aold[2][4];
        if (MODE == 0 && !first) {
#pragma unroll
            for (int cc = 0; cc < 2; ++cc)
#pragma unroll
                for (int r = 0; r < 4; ++r)
                    aold[cc][r] = avgrow[(size_t)(lg * 4 + r) * Ln +
                                         (c0 + cc) * 64 + wn * 16 + l15];
        }
        // stage P (hi/lo) into wave-private LDS
#pragma unroll
        for (int cc = 0; cc < 2; ++cc)
#pragma unroll
            for (int r = 0; r < 4; ++r) {
                float pv = sv[2 * p + cc][r] * invl[r];
                sv[2 * p + cc][r] = pv;
                ushort ph = f2b(pv);
                int off = (lg * 4 + r) * PWST + cc * 16 + l15;
                pwh[off] = ph;
                pwl[off] = f2b(pv - b2f(ph));
            }
        // V A-fragments
        int kcol = (lg < 2 ? c0 : c1) * 64 + wn * 16 + (lg & 1) * 8;
        bf16x8 va0 = *(const bf16x8*)(vbase + (size_t)(0 * 16 + l15) * Ln + kcol);
        bf16x8 va1 = *(const bf16x8*)(vbase + (size_t)(1 * 16 + l15) * Ln + kcol);
        bf16x8 va2 = *(const bf16x8*)(vbase + (size_t)(2 * 16 + l15) * Ln + kcol);
        bf16x8 va3 = *(const bf16x8*)(vbase + (size_t)(3 * 16 + l15) * Ln + kcol);
        // B fragments from own LDS (same-wave RAW: compiler lgkmcnt)
        bf16x8 pbh = *(const bf16x8*)&pwh[l15 * PWST + lg * 8];
        bf16x8 pbl = *(const bf16x8*)&pwl[l15 * PWST + lg * 8];
        acco[0] = __builtin_amdgcn_mfma_f32_16x16x32_bf16(va0, pbh, acco[0], 0, 0, 0);
        acco[1] = __builtin_amdgcn_mfma_f32_16x16x32_bf16(va1, pbh, acco[1], 0, 0, 0);
        acco[2] = __builtin_amdgcn_mfma_f32_16x16x32_bf16(va2, pbh, acco[2], 0, 0, 0);
        acco[3] = __builtin_amdgcn_mfma_f32_16x16x32_bf16(va3, pbh, acco[3], 0, 0, 0);
        acco[0] = __builtin_amdgcn_mfma_f32_16x16x32_bf16(va0, pbl, acco[0], 0, 0, 0);
        acco[1] = __builtin_amdgcn_mfma_f32_16x16x32_bf16(va1, pbl, acco[1], 0, 0, 0);
        acco[2] = __builtin_amdgcn_mfma_f32_16x16x32_bf16(va2, pbl, acco[2], 0, 0, 0);
        acco[3] = __builtin_amdgcn_mfma_f32_16x16x32_bf16(va3, pbl, acco[3], 0, 0, 0);
        if (MODE == 0) {
#pragma unroll
            for (int cc = 0; cc < 2; ++cc)
#pragma unroll
                for (int r = 0; r < 4; ++r) {
                    float v = 0.25f * sv[2 * p + cc][r];
                    if (!first) v += aold[cc][r];
                    avgrow[(size_t)(lg * 4 + r) * Ln + (c0 + cc) * 64 + wn * 16 + l15] = v;
                }
        } else if (MODE == 1) {
            // tile-linear P store: 512B contiguous per wave per cc
            size_t tb = ((((size_t)bid * 8 + w) * 4 + p) * 2) * 256 + (size_t)lane * 4;
            ushort4 ph0 = *(const ushort4*)&pwh[iw * PWST + 0 * 16 + jq * 4];
            ushort4 ph1 = *(const ushort4*)&pwh[iw * PWST + 1 * 16 + jq * 4];
            *(ushort4*)&Pout[tb] = ph0;
            *(ushort4*)&Pout[tb + 256] = ph1;
        } else {
            // MODE 2: read P0..P2 tile-linear, add own P, write avg f32
#pragma unroll
            for (int cc = 0; cc < 2; ++cc) {
                int c = c0 + cc;
                size_t tb = ((((size_t)bid * 8 + w) * 4 + p) * 2 + cc) * 256 +
                            (size_t)lane * 4;
                ushort4 p0 = *(const ushort4*)&Pout[tb];
                ushort4 p1 = *(const ushort4*)&Pout[(size_t)PELEMS + tb];
                ushort4 p2 = *(const ushort4*)&Pout[(size_t)2 * PELEMS + tb];
                ushort4 p3 = *(const ushort4*)&pwh[iw * PWST + cc * 16 + jq * 4];
                const ushort* q0 = (const ushort*)&p0;
                const ushort* q1 = (const ushort*)&p1;
                const ushort* q2 = (const ushort*)&p2;
                const ushort* q3 = (const ushort*)&p3;
                size_t base = ((size_t)(bh * Ln) + i0 + iw) * Ln +
                              c * 64 + wn * 16 + jq * 4;
                float4 o;
                float* op_ = (float*)&o;
#pragma unroll
                for (int k = 0; k < 4; ++k)
                    op_[k] = 0.25f * (b2f(q0[k]) + b2f(q1[k]) + b2f(q2[k]) + b2f(q3[k]));
                *(float4*)&avg[base] = o;
            }
        }
    }

    // ---- reduce partial O across 8 waves (Opart aliases Pw) ------------------
    __syncthreads();   // all PV done; Pw region dead
    {
        float* op = (float*)&uni[wn * 4096];
        if (wc == 1) {
#pragma unroll
            for (int dg = 0; dg < 4; ++dg)
#pragma unroll
                for (int r = 0; r < 4; ++r)
                    op[(dg * 16 + lg * 4 + r) * 16 + l15] = acco[dg][r];
        }
    }
    __syncthreads();
    {
        float* op = (float*)&uni[wn * 4096];
        if (wc == 0) {
#pragma unroll
            for (int dg = 0; dg < 4; ++dg)
#pragma unroll
                for (int r = 0; r < 4; ++r)
                    op[(dg * 16 + lg * 4 + r) * 16 + l15] += acco[dg][r];
        }
    }
    __syncthreads();
#pragma unroll
    for (int k = 0; k < 2; ++k) {
        int idx = t + 512 * k;          // idx = d*16 + i
        float v = ((const float*)&uni[0])[idx] + ((const float*)&uni[4096])[idx] +
                  ((const float*)&uni[8192])[idx] + ((const float*)&uni[12288])[idx];
        int dd = idx >> 4, ii = idx & 15;
        ctx[(size_t)(b * Ln + i0 + ii) * Dn + hh * DKn + dd] = f2b(v);
    }
}

// ---------------------------------------------------------------------------
__global__ __launch_bounds__(256) void layernorm_k(const ushort* __restrict__ X,
                                                   const float* __restrict__ g,
                                                   const float* __restrict__ bta,
                                                   ushort* __restrict__ Y) {
    int w = threadIdx.x >> 6, lane = threadIdx.x & 63;
    int row = blockIdx.x * 4 + w;
    const ushort* xr = X + (size_t)row * Dn;
    float x[4];
#pragma unroll
    for (int ii = 0; ii < 4; ++ii) x[ii] = b2f(xr[lane + 64 * ii]);
    float s = x[0] + x[1] + x[2] + x[3];
#pragma unroll
    for (int m = 1; m < 64; m <<= 1) s += __shfl_xor(s, m, 64);
    float mu = s * (1.0f / 256.0f);
    float vs = 0.f;
#pragma unroll
    for (int ii = 0; ii < 4; ++ii) {
        float d = x[ii] - mu;
        vs += d * d;
    }
#pragma unroll
    for (int m = 1; m < 64; m <<= 1) vs += __shfl_xor(vs, m, 64);
    float rs = rsqrtf(vs * (1.0f / 256.0f) + 1e-5f);
#pragma unroll
    for (int ii = 0; ii < 4; ++ii) {
        int d = lane + 64 * ii;
        Y[(size_t)row * Dn + d] = f2b((x[ii] - mu) * rs * g[d] + bta[d]);
    }
}

// ---------------------------------------------------------------------------
__global__ __launch_bounds__(256) void mean_part_k(const ushort* __restrict__ Hb,
                                                   float* __restrict__ part) {
    int blk = blockIdx.x;            // 64 = 4 b x 16 groups
    int b = blk >> 4, g = blk & 15;
    int d = threadIdx.x;
    float s = 0.f;
#pragma unroll
    for (int r = 0; r < 64; ++r)
        s += b2f(Hb[(size_t)(b * Ln + g * 64 + r) * Dn + d]);
    part[(size_t)blk * Dn + d] = s;
}
__global__ __launch_bounds__(256) void mean_final_k(const float* __restrict__ part,
                                                    float* __restrict__ out) {
    int b = blockIdx.x, d = threadIdx.x;
    float s = 0.f;
#pragma unroll
    for (int g = 0; g < 16; ++g) s += part[(size_t)(b * 16 + g) * Dn + d];
    out[b * Dn + d] = s * (1.0f / (float)Ln);
}

// ---------------------------------------------------------------------------
extern "C" void kernel_launch(void* const* d_in, const int* in_sizes, int n_in,
                              void* d_out, int out_size, void* d_ws, size_t ws_size,
                              hipStream_t stream) {
    const float* x    = (const float*)d_in[0];
    const float* emb  = (const float*)d_in[1];
    const float* Wq   = (const float*)d_in[2];
    const float* bq   = (const float*)d_in[3];
    const float* Wk   = (const float*)d_in[4];
    const float* bk   = (const float*)d_in[5];
    const float* Wv   = (const float*)d_in[6];
    const float* bv   = (const float*)d_in[7];
    const float* Wo   = (const float*)d_in[8];
    const float* bo   = (const float*)d_in[9];
    const float* rk   = (const float*)d_in[10];
    const float* rb   = (const float*)d_in[11];
    const float* ln1g = (const float*)d_in[12];
    const float* ln1b = (const float*)d_in[13];
    const float* W1   = (const float*)d_in[14];
    const float* b1   = (const float*)d_in[15];
    const float* W2   = (const float*)d_in[16];
    const float* b2   = (const float*)d_in[17];
    const float* ln2g = (const float*)d_in[18];
    const float* ln2b = (const float*)d_in[19];

    float* out = (float*)d_out;
    float* avg = out + Bn * Dn;

    char* ws = (char*)d_ws;
    const size_t MB = 1024 * 1024;
    ushort* hb   = (ushort*)(ws);             // 2 MB
    ushort* qkvb = (ushort*)(ws + 2 * MB);    // 6 MB
    ushort* ctxb = (ushort*)(ws + 8 * MB);    // 2 MB
    ushort* t1   = (ushort*)(ws + 10 * MB);   // 2 MB
    ushort* ffb  = (ushort*)(ws + 12 * MB);   // 8 MB
    ushort* qkvT = (ushort*)(ws + 20 * MB);   // 1.5 MB
    ushort* WoT  = (ushort*)(ws + 22 * MB);   // 0.5 MB
    ushort* W1T  = (ushort*)(ws + 23 * MB);   // 2 MB
    ushort* W2T  = (ushort*)(ws + 25 * MB);   // 2 MB
    float*  bqkv = (float*)(ws + 27 * MB);
    float*  bkT  = (float*)(ws + 27 * MB + 65536);
    float*  bbT  = (float*)(ws + 27 * MB + 131072);
    ushort* Vt   = (ushort*)(ws + 30 * MB);   // 2 MB
    float*  mpart= (float*)(ws + 33 * MB);    // 64 KB
    ushort* Pbuf = (ushort*)(ws + 36 * MB);   // 3 x 32 MB used (mode 1/2)

    const size_t need = 36 * MB + (size_t)3 * PELEMS * sizeof(ushort);
    const bool fancy = (ws_size >= need);

    embed_k<<<NTOK, 256, 0, stream>>>(x, emb, hb);
    relbias_k<<<64, 256, 0, stream>>>(rk, rb, bkT, bbT);
    prep_bias<<<12, 256, 0, stream>>>(bq, bk, bv, bqkv);

    dim3 t88(8, 8, NLn);
    transpose_cvt<<<t88, 256, 0, stream>>>(Wq, qkvT + 0,      256, 256, 65536, 196608);
    transpose_cvt<<<t88, 256, 0, stream>>>(Wk, qkvT + 65536,  256, 256, 65536, 196608);
    transpose_cvt<<<t88, 256, 0, stream>>>(Wv, qkvT + 131072, 256, 256, 65536, 196608);
    transpose_cvt<<<t88, 256, 0, stream>>>(Wo, WoT,           256, 256, 65536, 65536);
    transpose_cvt<<<dim3(32, 8, NLn), 256, 0, stream>>>(W1, W1T, 256, 1024, 262144, 262144);
    transpose_cvt<<<dim3(8, 32, NLn), 256, 0, stream>>>(W2, W2T, 1024, 256, 262144, 262144);

    for (int l = 0; l < NLn; ++l) {
        // QKV projection (V written transposed into Vt via epilogue);
        // layers 1..3 fuse previous layer's ln2 into A.
        if (l == 0) {
            gemm_mfma<0><<<dim3(12, 64), 256, 0, stream>>>(
                hb, qkvT + (size_t)l * 196608, bqkv + l * QKVW, qkvb,
                NTOK, QKVW, Dn, 0, nullptr, nullptr, Vt);
        } else {
            gemm_mfma<1><<<dim3(12, 64), 256, 0, stream>>>(
                hb, qkvT + (size_t)l * 196608, bqkv + l * QKVW, qkvb,
                NTOK, QKVW, Dn, 0, ln2g + (l - 1) * 256, ln2b + (l - 1) * 256, Vt);
        }
        if (fancy) {
            if (l < 3) {
                attn_fused<1><<<1024, 512, 0, stream>>>(
                    qkvb, Vt, bkT + l * Hn * Ln, bbT + l * Hn * Ln, ctxb, avg,
                    Pbuf + (size_t)l * PELEMS, 0);
            } else {
                attn_fused<2><<<1024, 512, 0, stream>>>(
                    qkvb, Vt, bkT + l * Hn * Ln, bbT + l * Hn * Ln, ctxb, avg,
                    Pbuf, 0);
            }
        } else {
            attn_fused<0><<<1024, 512, 0, stream>>>(
                qkvb, Vt, bkT + l * Hn * Ln, bbT + l * Hn * Ln, ctxb, avg,
                (ushort*)Pbuf, (l == 0) ? 1 : 0);
        }
        gemm_mfma<0><<<dim3(4, 64), 256, 0, stream>>>(
            ctxb, WoT + (size_t)l * 65536, bo + l * 256, t1,
            NTOK, Dn, Dn, 0, nullptr, nullptr, nullptr);
        // FF1 with fused ln1 + exact GELU
        gemm_mfma<1><<<dim3(16, 64), 256, 0, stream>>>(
            t1, W1T + (size_t)l * 262144, b1 + l * FFn, ffb,
            NTOK, FFn, Dn, 1, ln1g + l * 256, ln1b + l * 256, nullptr);
        gemm_mfma<0><<<dim3(4, 64), 256, 0, stream>>>(
            ffb, W2T + (size_t)l * 262144, b2 + l * 256, hb,
            NTOK, Dn, FFn, 0, nullptr, nullptr, nullptr);
    }
    // final ln2 (layer 3) before the mean
    layernorm_k<<<NTOK / 4, 256, 0, stream>>>(
        hb, ln2g + 3 * 256, ln2b + 3 * 256, hb);
    mean_part_k<<<64, 256, 0, stream>>>(hb, mpart);
    mean_final_k<<<Bn, 256, 0, stream>>>(mpart, out);
}